// Round 1
// baseline (5271.593 us; speedup 1.0000x reference)
//
#include <hip/hip_runtime.h>
#include <hip/hip_fp16.h>

// Fused 2-layer LSTM (I=14,H=64,T=256,B=8192) + FC head, single persistent kernel.
// - batch is embarrassingly parallel: block = 32 batch rows, loops all 256 timesteps.
// - weights fp16 in LDS (104KB), fp32 accumulate. h/c state fp32; c in registers,
//   h in per-wave-private LDS slices -> NO __syncthreads in the T-loop.
// - lane l owns hidden unit l (gate rows l, 64+l, 128+l, 192+l) for 4 batch rows.

#define TT 256
#define II 14
#define HH 64
#define BB 32
#define NTHREADS 512

// LDS map (bytes):
//  ws0i  [4][4][64] chunks of 4 half   :      0 ..   8192
//  ws0h  [16][4][64] chunks of 4 half  :   8192 ..  40960
//  ws1i                                :  40960 ..  73728
//  ws1h                                :  73728 .. 106496
//  hbuf0 [32][64] f32                  : 106496 .. 114688
//  hbuf1 [32][64] f32                  : 114688 .. 122880
//  xs    [32][16] f32                  : 122880 .. 124928
#define SMEM_BYTES 124928

__device__ __forceinline__ float sigm(float x) { return 1.0f / (1.0f + __expf(-x)); }
__device__ __forceinline__ float tanh_(float x) { return 1.0f - 2.0f / (__expf(2.0f * x) + 1.0f); }

// One GEMM part: acc[bi][gi] += sum_j W[gi*64+l][j] * op[bi][j],  j = 4*NJ4 values.
// W LDS layout: chunk c = (j4*4+gi)*64 + l holds 4 halfs = W[gi*64+l][4*j4 .. 4*j4+3].
template <int NJ4, int PITCH>  // PITCH in floats between operand rows
__device__ __forceinline__ void mm_part(const __half2* __restrict__ W,
                                        const float* opbase, int l,
                                        float (&acc)[4][4]) {
#pragma unroll 4
  for (int j4 = 0; j4 < NJ4; ++j4) {
    float4 xv[4];
#pragma unroll
    for (int bi = 0; bi < 4; ++bi)
      xv[bi] = *(const float4*)(opbase + bi * PITCH + j4 * 4);  // wave-uniform broadcast
#pragma unroll
    for (int gi = 0; gi < 4; ++gi) {
      const int c = (((j4 << 2) + gi) << 6) + l;
      const float2 wa = __half22float2(W[2 * c]);
      const float2 wb = __half22float2(W[2 * c + 1]);
#pragma unroll
      for (int bi = 0; bi < 4; ++bi) {
        acc[bi][gi] = fmaf(wa.x, xv[bi].x, acc[bi][gi]);
        acc[bi][gi] = fmaf(wa.y, xv[bi].y, acc[bi][gi]);
        acc[bi][gi] = fmaf(wb.x, xv[bi].z, acc[bi][gi]);
        acc[bi][gi] = fmaf(wb.y, xv[bi].w, acc[bi][gi]);
      }
    }
  }
}

__global__ void __launch_bounds__(NTHREADS, 2) fused_lstm(
    const float* __restrict__ x,
    const float* __restrict__ w_ih0, const float* __restrict__ w_hh0,
    const float* __restrict__ b_ih0, const float* __restrict__ b_hh0,
    const float* __restrict__ w_ih1, const float* __restrict__ w_hh1,
    const float* __restrict__ b_ih1, const float* __restrict__ b_hh1,
    const float* __restrict__ w_fc1, const float* __restrict__ b_fc1,
    const float* __restrict__ w_fc2, const float* __restrict__ b_fc2,
    float* __restrict__ out) {
  extern __shared__ char smem[];
  __half2* ws0i = (__half2*)(smem);
  __half2* ws0h = (__half2*)(smem + 8192);
  __half2* ws1i = (__half2*)(smem + 40960);
  __half2* ws1h = (__half2*)(smem + 73728);
  float* hbuf0 = (float*)(smem + 106496);
  float* hbuf1 = (float*)(smem + 114688);
  float* xs = (float*)(smem + 122880);

  const int tid = threadIdx.x;
  const int wv = tid >> 6;
  const int l = tid & 63;
  const int b0 = blockIdx.x * BB;
  const int bbase = wv * 4;  // this wave's 4 batch rows (block-local)

  // ---------------- prologue: stage weights fp32 -> fp16 LDS ----------------
  {
    const float* srcs[3] = {w_hh0, w_ih1, w_hh1};
    __half2* dsts[3] = {ws0h, ws1i, ws1h};
    for (int m = 0; m < 3; ++m) {
      const float* src = srcs[m];
      __half2* dst = dsts[m];
      for (int idx = tid; idx < 4096; idx += NTHREADS) {
        const int g = idx >> 4, j4 = idx & 15;
        const float4 w = *(const float4*)(src + g * 64 + j4 * 4);
        const int c = ((j4 * 4 + (g >> 6)) * 64 + (g & 63)) * 2;
        dst[c] = __floats2half2_rn(w.x, w.y);
        dst[c + 1] = __floats2half2_rn(w.z, w.w);
      }
    }
    // w_ih0 [256][14] padded to K=16 with zeros
    for (int idx = tid; idx < 1024; idx += NTHREADS) {
      const int g = idx >> 2, j4 = idx & 3;
      float v[4];
#pragma unroll
      for (int jj = 0; jj < 4; ++jj) {
        const int k = j4 * 4 + jj;
        v[jj] = (k < II) ? w_ih0[g * II + k] : 0.0f;
      }
      const int c = ((j4 * 4 + (g >> 6)) * 64 + (g & 63)) * 2;
      ws0i[c] = __floats2half2_rn(v[0], v[1]);
      ws0i[c + 1] = __floats2half2_rn(v[2], v[3]);
    }
  }
  for (int i = tid; i < BB * HH; i += NTHREADS) {
    hbuf0[i] = 0.0f;
    hbuf1[i] = 0.0f;
  }
  xs[tid] = 0.0f;  // BB*16 == 512 == NTHREADS (pads k=14,15 stay 0 forever)

  float bias0[4], bias1[4];
#pragma unroll
  for (int gi = 0; gi < 4; ++gi) {
    bias0[gi] = b_ih0[gi * 64 + l] + b_hh0[gi * 64 + l];
    bias1[gi] = b_ih1[gi * 64 + l] + b_hh1[gi * 64 + l];
  }
  float c0[4] = {0.f, 0.f, 0.f, 0.f};
  float c1[4] = {0.f, 0.f, 0.f, 0.f};

  __syncthreads();

  // x fetch: lanes 0..55 each own one (batch row, input dim) pair
  const int bi_x = l / II;
  const int k_x = l - bi_x * II;
  const float* xptr = x + (size_t)(b0 + bbase + bi_x) * (TT * II) + k_x;
  float* xs_w = xs + bbase * 16;
  float* hb0_w = hbuf0 + bbase * 64;
  float* hb1_w = hbuf1 + bbase * 64;

  float xreg = (l < 56) ? xptr[0] : 0.0f;

  for (int t = 0; t < TT; ++t) {
    // stage x(t) into LDS, prefetch x(t+1) (latency hidden under the 4 GEMM parts)
    if (l < 56) {
      xs_w[bi_x * 16 + k_x] = xreg;
      if (t + 1 < TT) xreg = xptr[(t + 1) * II];
    }

    // ---- layer 0 ----
    float acc0[4][4];
#pragma unroll
    for (int bi = 0; bi < 4; ++bi)
#pragma unroll
      for (int gi = 0; gi < 4; ++gi) acc0[bi][gi] = bias0[gi];

    mm_part<4, 16>(ws0i, xs_w, l, acc0);    // x projection (K=16 padded)
    mm_part<16, 64>(ws0h, hb0_w, l, acc0);  // recurrent (K=64)

#pragma unroll
    for (int bi = 0; bi < 4; ++bi) {
      const float ig = sigm(acc0[bi][0]);
      const float fg = sigm(acc0[bi][1]);
      const float gg = tanh_(acc0[bi][2]);
      const float og = sigm(acc0[bi][3]);
      c0[bi] = fmaf(fg, c0[bi], ig * gg);
      hb0_w[bi * 64 + l] = og * tanh_(c0[bi]);  // intra-wave only; lgkmcnt handles
    }

    // ---- layer 1 (input = fresh h0) ----
    float acc1[4][4];
#pragma unroll
    for (int bi = 0; bi < 4; ++bi)
#pragma unroll
      for (int gi = 0; gi < 4; ++gi) acc1[bi][gi] = bias1[gi];

    mm_part<16, 64>(ws1i, hb0_w, l, acc1);  // input projection (K=64)
    mm_part<16, 64>(ws1h, hb1_w, l, acc1);  // recurrent (K=64)

#pragma unroll
    for (int bi = 0; bi < 4; ++bi) {
      const float ig = sigm(acc1[bi][0]);
      const float fg = sigm(acc1[bi][1]);
      const float gg = tanh_(acc1[bi][2]);
      const float og = sigm(acc1[bi][3]);
      c1[bi] = fmaf(fg, c1[bi], ig * gg);
      hb1_w[bi * 64 + l] = og * tanh_(c1[bi]);
    }
  }

  // ---------------- FC head: z = relu(h2 @ W1^T + b1); out = z @ W2^T + b2 ----
  __syncthreads();                 // all waves done with weight LDS; safe to reuse
  float* zbuf = (float*)smem;      // [32][64] f32, reuses ws0i region
  const float4* w1r = (const float4*)(w_fc1 + l * 64);
  const float b1l = b_fc1[l];
#pragma unroll
  for (int bi = 0; bi < 4; ++bi) {
    const float4* hr = (const float4*)(hb1_w + bi * 64);
    float s = b1l;
#pragma unroll
    for (int j4 = 0; j4 < 16; ++j4) {
      const float4 h4 = hr[j4];
      const float4 w4 = w1r[j4];
      s = fmaf(h4.x, w4.x, s);
      s = fmaf(h4.y, w4.y, s);
      s = fmaf(h4.z, w4.z, s);
      s = fmaf(h4.w, w4.w, s);
    }
    zbuf[(bbase + bi) * 64 + l] = fmaxf(s, 0.0f);
  }
  if (l < 8) {  // 4 batch rows x 2 classes per wave; intra-wave read of zbuf
    const int bi = l >> 1, cc = l & 1;
    const float* zr = zbuf + (bbase + bi) * 64;
    float s = b_fc2[cc];
    for (int j = 0; j < 64; ++j) s = fmaf(w_fc2[cc * 64 + j], zr[j], s);
    out[(size_t)(b0 + bbase + bi) * 2 + cc] = s;
  }
}

extern "C" void kernel_launch(void* const* d_in, const int* in_sizes, int n_in,
                              void* d_out, int out_size, void* d_ws, size_t ws_size,
                              hipStream_t stream) {
  (void)in_sizes; (void)n_in; (void)d_ws; (void)ws_size; (void)out_size;
  const float* x = (const float*)d_in[0];
  const float* w_ih0 = (const float*)d_in[1];
  const float* w_hh0 = (const float*)d_in[2];
  const float* b_ih0 = (const float*)d_in[3];
  const float* b_hh0 = (const float*)d_in[4];
  const float* w_ih1 = (const float*)d_in[5];
  const float* w_hh1 = (const float*)d_in[6];
  const float* b_ih1 = (const float*)d_in[7];
  const float* b_hh1 = (const float*)d_in[8];
  const float* w_fc1 = (const float*)d_in[9];
  const float* b_fc1 = (const float*)d_in[10];
  const float* w_fc2 = (const float*)d_in[11];
  const float* b_fc2 = (const float*)d_in[12];

  hipFuncSetAttribute((const void*)fused_lstm,
                      hipFuncAttributeMaxDynamicSharedMemorySize, SMEM_BYTES);
  fused_lstm<<<dim3(8192 / BB), dim3(NTHREADS), SMEM_BYTES, stream>>>(
      x, w_ih0, w_hh0, b_ih0, b_hh0, w_ih1, w_hh1, b_ih1, b_hh1,
      w_fc1, b_fc1, w_fc2, b_fc2, (float*)d_out);
}

// Round 2
// 2605.422 us; speedup vs baseline: 2.0233x; 2.0233x over previous
//
#include <hip/hip_runtime.h>
#include <hip/hip_fp16.h>

// Fused 2-layer LSTM (I=14,H=64,T=256,B=8192) + FC head. One persistent kernel.
// R2: v_dot2_f32_f16 (fp16 weights AND operands, fp32 accum), conflict-free
// lane-stride-16B weight layout, 4 waves x 8 batch rows (halves weight LDS BW).

#define TT 256
#define II 14
#define HH 64
#define BB 32
#define BI 8          // batch rows per wave
#define NTHREADS 256  // 4 waves

// LDS map (bytes):
//  ws0i  [2k8][4g][64l] x16B :      0 ..   8192
//  ws0h  [8k8][4g][64l] x16B :   8192 ..  40960
//  ws1i                      :  40960 ..  73728
//  ws1h                      :  73728 .. 106496
//  hbuf0 [32][64] f16        : 106496 .. 110592
//  hbuf1 [32][64] f16        : 110592 .. 114688
//  xs    [32][16] f16        : 114688 .. 115712
#define SMEM_BYTES 115712

typedef _Float16 h2_t __attribute__((ext_vector_type(2)));

__device__ __forceinline__ float dot2(unsigned w, unsigned o, float acc) {
#if __has_builtin(__builtin_amdgcn_fdot2)
  return __builtin_amdgcn_fdot2(__builtin_bit_cast(h2_t, w),
                                __builtin_bit_cast(h2_t, o), acc, false);
#else
  h2_t wv = __builtin_bit_cast(h2_t, w), ov = __builtin_bit_cast(h2_t, o);
  acc = fmaf((float)wv[0], (float)ov[0], acc);
  return fmaf((float)wv[1], (float)ov[1], acc);
#endif
}

__device__ __forceinline__ unsigned pack2(float a, float b) {
  h2_t p;
  p[0] = (_Float16)a;
  p[1] = (_Float16)b;
  return __builtin_bit_cast(unsigned, p);
}

__device__ __forceinline__ float sigm(float x) { return 1.0f / (1.0f + __expf(-x)); }
__device__ __forceinline__ float tanh_(float x) { return 1.0f - 2.0f / (__expf(2.0f * x) + 1.0f); }

// acc[bi][gi] += sum over 8*NK8 k of W[gi*64+l][k] * op[bi][k]
// weight chunk (k8*4+gi)*64+l holds halfs W[gi*64+l][8k8..8k8+7] (16B, lane-stride 16B)
template <int NK8, int OPPITCH>
__device__ __forceinline__ void mm_dot2(const char* __restrict__ Wbase,
                                        const _Float16* __restrict__ op, int l,
                                        float (&acc)[BI][4]) {
#pragma unroll
  for (int k8 = 0; k8 < NK8; ++k8) {
    int4 ov[BI];
#pragma unroll
    for (int bi = 0; bi < BI; ++bi)
      ov[bi] = *(const int4*)(op + bi * OPPITCH + k8 * 8);  // wave-uniform broadcast
#pragma unroll
    for (int gi = 0; gi < 4; ++gi) {
      const int4 wv = *(const int4*)(Wbase + ((((k8 << 2) + gi) << 6) + l) * 16);
#pragma unroll
      for (int bi = 0; bi < BI; ++bi) {
        acc[bi][gi] = dot2(wv.x, ov[bi].x, acc[bi][gi]);
        acc[bi][gi] = dot2(wv.y, ov[bi].y, acc[bi][gi]);
        acc[bi][gi] = dot2(wv.z, ov[bi].z, acc[bi][gi]);
        acc[bi][gi] = dot2(wv.w, ov[bi].w, acc[bi][gi]);
      }
    }
  }
}

__global__ void __launch_bounds__(NTHREADS, 1) fused_lstm(
    const float* __restrict__ x,
    const float* __restrict__ w_ih0, const float* __restrict__ w_hh0,
    const float* __restrict__ b_ih0, const float* __restrict__ b_hh0,
    const float* __restrict__ w_ih1, const float* __restrict__ w_hh1,
    const float* __restrict__ b_ih1, const float* __restrict__ b_hh1,
    const float* __restrict__ w_fc1, const float* __restrict__ b_fc1,
    const float* __restrict__ w_fc2, const float* __restrict__ b_fc2,
    float* __restrict__ out) {
  extern __shared__ char smem[];
  char* ws0i = smem;
  char* ws0h = smem + 8192;
  char* ws1i = smem + 40960;
  char* ws1h = smem + 73728;
  _Float16* hbuf0 = (_Float16*)(smem + 106496);
  _Float16* hbuf1 = (_Float16*)(smem + 110592);
  _Float16* xs = (_Float16*)(smem + 114688);

  const int tid = threadIdx.x;
  const int wv = tid >> 6;
  const int l = tid & 63;
  const int b0 = blockIdx.x * BB;
  const int bbase = wv * BI;

  // ---- stage weights fp32 -> fp16 LDS, chunk (k8*4+gi)*64+l = row gi*64+l, halfs 8k8.. ----
  {
    const float* srcs[3] = {w_hh0, w_ih1, w_hh1};
    char* dsts[3] = {ws0h, ws1i, ws1h};
    for (int m = 0; m < 3; ++m) {
      const float* src = srcs[m];
      char* dst = dsts[m];
      for (int idx = tid; idx < 2048; idx += NTHREADS) {  // 256 rows x 8 k8-chunks
        const int g = idx >> 3, k8 = idx & 7;
        const float4 a = *(const float4*)(src + g * 64 + k8 * 8);
        const float4 b = *(const float4*)(src + g * 64 + k8 * 8 + 4);
        int4 w;
        w.x = pack2(a.x, a.y); w.y = pack2(a.z, a.w);
        w.z = pack2(b.x, b.y); w.w = pack2(b.z, b.w);
        *(int4*)(dst + (((k8 << 2) + (g >> 6)) * 64 + (g & 63)) * 16) = w;
      }
    }
    for (int idx = tid; idx < 512; idx += NTHREADS) {  // w_ih0: K=14 padded to 16
      const int g = idx >> 1, k8 = idx & 1;
      float v[8];
#pragma unroll
      for (int j = 0; j < 8; ++j) {
        const int k = k8 * 8 + j;
        v[j] = (k < II) ? w_ih0[g * II + k] : 0.0f;
      }
      int4 w;
      w.x = pack2(v[0], v[1]); w.y = pack2(v[2], v[3]);
      w.z = pack2(v[4], v[5]); w.w = pack2(v[6], v[7]);
      *(int4*)(ws0i + (((k8 << 2) + (g >> 6)) * 64 + (g & 63)) * 16) = w;
    }
  }
  // zero h-state and xs (pads k=14,15 stay zero forever)
  {
    unsigned* z = (unsigned*)(smem + 106496);
    for (int i = tid; i < 2304; i += NTHREADS) z[i] = 0u;
  }

  float bias0[4], bias1[4];
#pragma unroll
  for (int gi = 0; gi < 4; ++gi) {
    bias0[gi] = b_ih0[gi * 64 + l] + b_hh0[gi * 64 + l];
    bias1[gi] = b_ih1[gi * 64 + l] + b_hh1[gi * 64 + l];
  }
  float c0[BI], c1[BI];
#pragma unroll
  for (int bi = 0; bi < BI; ++bi) c0[bi] = c1[bi] = 0.0f;

  __syncthreads();

  // x staging: 112 (row,k) pairs per wave; lane l owns idx l and l+64
  const int bi0_x = l / II, k0_x = l - bi0_x * II;
  const int idx1 = l + 64;
  const bool has1 = idx1 < BI * II;
  const int bi1_x = idx1 / II, k1_x = idx1 - bi1_x * II;
  const float* xp0 = x + (size_t)(b0 + bbase + bi0_x) * (TT * II) + k0_x;
  const float* xp1 = x + (size_t)(b0 + bbase + (has1 ? bi1_x : 0)) * (TT * II) + k1_x;
  _Float16* xs_w = xs + bbase * 16;
  _Float16* hb0_w = hbuf0 + bbase * 64;
  _Float16* hb1_w = hbuf1 + bbase * 64;

  float xr0 = xp0[0];
  float xr1 = has1 ? xp1[0] : 0.0f;

  for (int t = 0; t < TT; ++t) {
    xs_w[bi0_x * 16 + k0_x] = (_Float16)xr0;
    if (has1) xs_w[bi1_x * 16 + k1_x] = (_Float16)xr1;
    if (t + 1 < TT) {
      xr0 = xp0[(t + 1) * II];
      if (has1) xr1 = xp1[(t + 1) * II];
    }

    // ---- layer 0 ----
    float acc0[BI][4];
#pragma unroll
    for (int bi = 0; bi < BI; ++bi)
#pragma unroll
      for (int gi = 0; gi < 4; ++gi) acc0[bi][gi] = bias0[gi];
    mm_dot2<2, 16>(ws0i, xs_w, l, acc0);
    mm_dot2<8, 64>(ws0h, hb0_w, l, acc0);
#pragma unroll
    for (int bi = 0; bi < BI; ++bi) {
      const float ig = sigm(acc0[bi][0]);
      const float fg = sigm(acc0[bi][1]);
      const float gg = tanh_(acc0[bi][2]);
      const float og = sigm(acc0[bi][3]);
      c0[bi] = fmaf(fg, c0[bi], ig * gg);
      hb0_w[bi * 64 + l] = (_Float16)(og * tanh_(c0[bi]));  // intra-wave only
    }

    // ---- layer 1 ----
    float acc1[BI][4];
#pragma unroll
    for (int bi = 0; bi < BI; ++bi)
#pragma unroll
      for (int gi = 0; gi < 4; ++gi) acc1[bi][gi] = bias1[gi];
    mm_dot2<8, 64>(ws1i, hb0_w, l, acc1);
    mm_dot2<8, 64>(ws1h, hb1_w, l, acc1);
#pragma unroll
    for (int bi = 0; bi < BI; ++bi) {
      const float ig = sigm(acc1[bi][0]);
      const float fg = sigm(acc1[bi][1]);
      const float gg = tanh_(acc1[bi][2]);
      const float og = sigm(acc1[bi][3]);
      c1[bi] = fmaf(fg, c1[bi], ig * gg);
      hb1_w[bi * 64 + l] = (_Float16)(og * tanh_(c1[bi]));
    }
  }

  // ---- FC head ----
  __syncthreads();             // everyone done with weight LDS
  float* zbuf = (float*)smem;  // [32][64] f32 reuses ws0i (8KB)
  {
    const float4* w1r = (const float4*)(w_fc1 + l * 64);
    const float b1l = b_fc1[l];
#pragma unroll
    for (int bi = 0; bi < BI; ++bi) {
      const _Float16* hr = hb1_w + bi * 64;
      float s = b1l;
#pragma unroll
      for (int j4 = 0; j4 < 16; ++j4) {
        const float4 w4 = w1r[j4];
        s = fmaf((float)hr[j4 * 4 + 0], w4.x, s);
        s = fmaf((float)hr[j4 * 4 + 1], w4.y, s);
        s = fmaf((float)hr[j4 * 4 + 2], w4.z, s);
        s = fmaf((float)hr[j4 * 4 + 3], w4.w, s);
      }
      zbuf[(bbase + bi) * 64 + l] = fmaxf(s, 0.0f);
    }
  }
  __builtin_amdgcn_s_waitcnt(0);  // zbuf writes visible within wave
  if (l < 2 * BI) {               // 8 rows x 2 classes per wave
    const int bi = l >> 1, cc = l & 1;
    const float* zr = zbuf + (bbase + bi) * 64;
    float s = b_fc2[cc];
    for (int j = 0; j < 64; ++j) s = fmaf(w_fc2[cc * 64 + j], zr[j], s);
    out[(size_t)(b0 + bbase + bi) * 2 + cc] = s;
  }
}

extern "C" void kernel_launch(void* const* d_in, const int* in_sizes, int n_in,
                              void* d_out, int out_size, void* d_ws, size_t ws_size,
                              hipStream_t stream) {
  (void)in_sizes; (void)n_in; (void)d_ws; (void)ws_size; (void)out_size;
  const float* x = (const float*)d_in[0];
  const float* w_ih0 = (const float*)d_in[1];
  const float* w_hh0 = (const float*)d_in[2];
  const float* b_ih0 = (const float*)d_in[3];
  const float* b_hh0 = (const float*)d_in[4];
  const float* w_ih1 = (const float*)d_in[5];
  const float* w_hh1 = (const float*)d_in[6];
  const float* b_ih1 = (const float*)d_in[7];
  const float* b_hh1 = (const float*)d_in[8];
  const float* w_fc1 = (const float*)d_in[9];
  const float* b_fc1 = (const float*)d_in[10];
  const float* w_fc2 = (const float*)d_in[11];
  const float* b_fc2 = (const float*)d_in[12];

  hipFuncSetAttribute((const void*)fused_lstm,
                      hipFuncAttributeMaxDynamicSharedMemorySize, SMEM_BYTES);
  fused_lstm<<<dim3(8192 / BB), dim3(NTHREADS), SMEM_BYTES, stream>>>(
      x, w_ih0, w_hh0, b_ih0, b_hh0, w_ih1, w_hh1, b_ih1, b_hh1,
      w_fc1, b_fc1, w_fc2, b_fc2, (float*)d_out);
}

// Round 3
// 842.176 us; speedup vs baseline: 6.2595x; 3.0937x over previous
//
#include <hip/hip_runtime.h>

// R3: MFMA-based fused 2-layer LSTM (I=14,H=64,T=256,B=8192) + FC head.
// Per timestep: gates = W[256,K] @ op[K,32batch] via v_mfma_f32_16x16x32_f16.
// Weights persist in VGPRs as A-fragments (wave w owns gate rows w*16..w*16+15
// of each gate type). LDS holds only h0/h1/x (fp16). 3 barriers/timestep.

#define TT 256
#define II 14
#define BB 32
#define NTHREADS 256
#define XP 40  // xs row pitch (halfs): 80B rows -> bank-friendly
#define HP 72  // hbuf row pitch (halfs): 144B rows -> bank-friendly

typedef _Float16 f16x8 __attribute__((ext_vector_type(8)));
typedef _Float16 f16x4 __attribute__((ext_vector_type(4)));
typedef float f32x4 __attribute__((ext_vector_type(4)));

__device__ __forceinline__ f32x4 MFMA16(f16x8 a, f16x8 b, f32x4 c) {
  return __builtin_amdgcn_mfma_f32_16x16x32_f16(a, b, c, 0, 0, 0);
}

__device__ __forceinline__ float sigm(float x) { return 1.0f / (1.0f + __expf(-x)); }
__device__ __forceinline__ float tanh_(float x) { return 1.0f - 2.0f / (__expf(2.0f * x) + 1.0f); }

__global__ void __launch_bounds__(NTHREADS, 1) fused_lstm(
    const float* __restrict__ x,
    const float* __restrict__ w_ih0, const float* __restrict__ w_hh0,
    const float* __restrict__ b_ih0, const float* __restrict__ b_hh0,
    const float* __restrict__ w_ih1, const float* __restrict__ w_hh1,
    const float* __restrict__ b_ih1, const float* __restrict__ b_hh1,
    const float* __restrict__ w_fc1, const float* __restrict__ b_fc1,
    const float* __restrict__ w_fc2, const float* __restrict__ b_fc2,
    float* __restrict__ out) {
  // LDS: hb1 [32][HP] f16 @0..4608 ; hb0 @4608..9216 ; xs [32][XP] @9216..11776
  // zbuf (FC phase only) overlays 4608..12800
  __shared__ char smem[12800];
  _Float16* hb1 = (_Float16*)smem;
  _Float16* hb0 = (_Float16*)(smem + 4608);
  _Float16* xs = (_Float16*)(smem + 9216);

  const int tid = threadIdx.x;
  const int w = tid >> 6;     // wave: owns gate rows w*16..w*16+15 per gate type
  const int l = tid & 63;
  const int row16 = l & 15;   // A: M row within tile / B,C,D: N col within tile
  const int kblk = l >> 4;    // A,B: k-block of 8 / C,D: row-block of 4
  const int b0 = blockIdx.x * BB;

  // ---- load weight A-fragments into registers (fp32 -> fp16) ----
  f16x8 a_ih0[4], a_hh0[4][2], a_ih1[4][2], a_hh1[4][2];
#pragma unroll
  for (int gt = 0; gt < 4; ++gt) {
    const int g = gt * 64 + w * 16 + row16;  // global gate row
    {
      f16x8 v;
#pragma unroll
      for (int j = 0; j < 8; ++j) {
        const int k = kblk * 8 + j;  // K padded 14 -> 32
        v[j] = (k < II) ? (_Float16)w_ih0[g * II + k] : (_Float16)0.0f;
      }
      a_ih0[gt] = v;
    }
#pragma unroll
    for (int ks = 0; ks < 2; ++ks) {
      const int ko = ks * 32 + kblk * 8;
      f16x8 v0, v1, v2;
#pragma unroll
      for (int j = 0; j < 8; ++j) v0[j] = (_Float16)w_hh0[g * 64 + ko + j];
#pragma unroll
      for (int j = 0; j < 8; ++j) v1[j] = (_Float16)w_ih1[g * 64 + ko + j];
#pragma unroll
      for (int j = 0; j < 8; ++j) v2[j] = (_Float16)w_hh1[g * 64 + ko + j];
      a_hh0[gt][ks] = v0;
      a_ih1[gt][ks] = v1;
      a_hh1[gt][ks] = v2;
    }
  }
  f32x4 bias0[4], bias1[4];
#pragma unroll
  for (int gt = 0; gt < 4; ++gt) {
#pragma unroll
    for (int r = 0; r < 4; ++r) {
      const int g = gt * 64 + w * 16 + kblk * 4 + r;  // C/D row mapping
      bias0[gt][r] = b_ih0[g] + b_hh0[g];
      bias1[gt][r] = b_ih1[g] + b_hh1[g];
    }
  }

  // zero LDS (hb0, hb1, xs incl. pads)
  for (int i = tid; i < 12800 / 4; i += NTHREADS) ((int*)smem)[i] = 0;

  // x staging: 448 (row,k) slots; thread covers tid and tid+256
  const int n0 = tid / II, k0 = tid - n0 * II;
  const bool has1 = (tid + NTHREADS) < BB * II;
  const int i1 = tid + NTHREADS;
  const int n1x = has1 ? (i1 / II) : 0;
  const int k1 = i1 - (i1 / II) * II;
  const float* xp0 = x + (size_t)(b0 + n0) * (TT * II) + k0;
  const float* xp1 = x + (size_t)(b0 + n1x) * (TT * II) + k1;

  __syncthreads();  // zeros done
  xs[n0 * XP + k0] = (_Float16)xp0[0];
  if (has1) xs[n1x * XP + k1] = (_Float16)xp1[0];
  __syncthreads();  // x(0) staged

  f32x4 c0s[2], c1s[2];
#pragma unroll
  for (int nt = 0; nt < 2; ++nt)
#pragma unroll
    for (int r = 0; r < 4; ++r) {
      c0s[nt][r] = 0.0f;
      c1s[nt][r] = 0.0f;
    }

  for (int t = 0; t < TT; ++t) {
    // ================= Phase A: layer 0 =================
    f32x4 acc[4][2];
#pragma unroll
    for (int gt = 0; gt < 4; ++gt) {
      acc[gt][0] = bias0[gt];
      acc[gt][1] = bias0[gt];
    }
    f16x8 bx[2], bh[2][2];
#pragma unroll
    for (int nt = 0; nt < 2; ++nt) {
      const int n = nt * 16 + row16;
      bx[nt] = *(const f16x8*)(xs + n * XP + kblk * 8);
#pragma unroll
      for (int ks = 0; ks < 2; ++ks)
        bh[nt][ks] = *(const f16x8*)(hb0 + n * HP + ks * 32 + kblk * 8);
    }
#pragma unroll
    for (int gt = 0; gt < 4; ++gt)
#pragma unroll
      for (int nt = 0; nt < 2; ++nt) {
        acc[gt][nt] = MFMA16(a_ih0[gt], bx[nt], acc[gt][nt]);
        acc[gt][nt] = MFMA16(a_hh0[gt][0], bh[nt][0], acc[gt][nt]);
        acc[gt][nt] = MFMA16(a_hh0[gt][1], bh[nt][1], acc[gt][nt]);
      }

    // prefetch x(t+1) (latency hidden under activation)
    float xn0 = 0.0f, xn1 = 0.0f;
    if (t + 1 < TT) {
      xn0 = xp0[(size_t)(t + 1) * II];
      if (has1) xn1 = xp1[(size_t)(t + 1) * II];
    }

    f16x4 h0p[2];
#pragma unroll
    for (int nt = 0; nt < 2; ++nt)
#pragma unroll
      for (int r = 0; r < 4; ++r) {
        const float ig = sigm(acc[0][nt][r]);
        const float fg = sigm(acc[1][nt][r]);
        const float gg = tanh_(acc[2][nt][r]);
        const float og = sigm(acc[3][nt][r]);
        const float c = fmaf(fg, c0s[nt][r], ig * gg);
        c0s[nt][r] = c;
        h0p[nt][r] = (_Float16)(og * tanh_(c));
      }

    __syncthreads();  // b1: all reads of hb0(t-1)/xs(t) done
    // ================= Phase B: publish h0(t), x(t+1) =================
#pragma unroll
    for (int nt = 0; nt < 2; ++nt)
      *(f16x4*)(hb0 + (nt * 16 + row16) * HP + w * 16 + kblk * 4) = h0p[nt];
    if (t + 1 < TT) {
      xs[n0 * XP + k0] = (_Float16)xn0;
      if (has1) xs[n1x * XP + k1] = (_Float16)xn1;
    }
    __syncthreads();  // b2: h0(t) visible

    // ================= Phase C: layer 1 =================
#pragma unroll
    for (int gt = 0; gt < 4; ++gt) {
      acc[gt][0] = bias1[gt];
      acc[gt][1] = bias1[gt];
    }
    f16x8 bg[2][2], bh1[2][2];
#pragma unroll
    for (int nt = 0; nt < 2; ++nt) {
      const int n = nt * 16 + row16;
#pragma unroll
      for (int ks = 0; ks < 2; ++ks) {
        bg[nt][ks] = *(const f16x8*)(hb0 + n * HP + ks * 32 + kblk * 8);
        bh1[nt][ks] = *(const f16x8*)(hb1 + n * HP + ks * 32 + kblk * 8);
      }
    }
#pragma unroll
    for (int gt = 0; gt < 4; ++gt)
#pragma unroll
      for (int nt = 0; nt < 2; ++nt) {
        acc[gt][nt] = MFMA16(a_ih1[gt][0], bg[nt][0], acc[gt][nt]);
        acc[gt][nt] = MFMA16(a_ih1[gt][1], bg[nt][1], acc[gt][nt]);
        acc[gt][nt] = MFMA16(a_hh1[gt][0], bh1[nt][0], acc[gt][nt]);
        acc[gt][nt] = MFMA16(a_hh1[gt][1], bh1[nt][1], acc[gt][nt]);
      }

    f16x4 h1p[2];
#pragma unroll
    for (int nt = 0; nt < 2; ++nt)
#pragma unroll
      for (int r = 0; r < 4; ++r) {
        const float ig = sigm(acc[0][nt][r]);
        const float fg = sigm(acc[1][nt][r]);
        const float gg = tanh_(acc[2][nt][r]);
        const float og = sigm(acc[3][nt][r]);
        const float c = fmaf(fg, c1s[nt][r], ig * gg);
        c1s[nt][r] = c;
        h1p[nt][r] = (_Float16)(og * tanh_(c));
      }

    __syncthreads();  // b3: all reads of hb1(t-1) done
    // ================= Phase D: publish h1(t) =================
#pragma unroll
    for (int nt = 0; nt < 2; ++nt)
      *(f16x4*)(hb1 + (nt * 16 + row16) * HP + w * 16 + kblk * 4) = h1p[nt];
    // no barrier: next Phase A touches only hb0/xs
  }
  __syncthreads();  // final h1(255) visible

  // ================= FC head =================
  float* zbuf = (float*)(smem + 4608);  // overlays hb0+xs (dead now)
  float4 w1r[16];
#pragma unroll
  for (int k4 = 0; k4 < 16; ++k4) w1r[k4] = *(const float4*)(w_fc1 + l * 64 + k4 * 4);
  const float b1l = b_fc1[l];
#pragma unroll
  for (int bi = 0; bi < 8; ++bi) {
    const int n = w * 8 + bi;
    float s = b1l;
#pragma unroll
    for (int k4 = 0; k4 < 16; ++k4) {
      const float4 wv = w1r[k4];
      s = fmaf((float)hb1[n * HP + k4 * 4 + 0], wv.x, s);
      s = fmaf((float)hb1[n * HP + k4 * 4 + 1], wv.y, s);
      s = fmaf((float)hb1[n * HP + k4 * 4 + 2], wv.z, s);
      s = fmaf((float)hb1[n * HP + k4 * 4 + 3], wv.w, s);
    }
    zbuf[n * 64 + l] = fmaxf(s, 0.0f);
  }
  __syncthreads();
  if (tid < 64) {
    const int n = tid >> 1, cc = tid & 1;
    float s = b_fc2[cc];
    for (int j = 0; j < 64; ++j) s = fmaf(w_fc2[cc * 64 + j], zbuf[n * 64 + j], s);
    out[(size_t)(b0 + n) * 2 + cc] = s;
  }
}

extern "C" void kernel_launch(void* const* d_in, const int* in_sizes, int n_in,
                              void* d_out, int out_size, void* d_ws, size_t ws_size,
                              hipStream_t stream) {
  (void)in_sizes; (void)n_in; (void)d_ws; (void)ws_size; (void)out_size;
  const float* x = (const float*)d_in[0];
  const float* w_ih0 = (const float*)d_in[1];
  const float* w_hh0 = (const float*)d_in[2];
  const float* b_ih0 = (const float*)d_in[3];
  const float* b_hh0 = (const float*)d_in[4];
  const float* w_ih1 = (const float*)d_in[5];
  const float* w_hh1 = (const float*)d_in[6];
  const float* b_ih1 = (const float*)d_in[7];
  const float* b_hh1 = (const float*)d_in[8];
  const float* w_fc1 = (const float*)d_in[9];
  const float* b_fc1 = (const float*)d_in[10];
  const float* w_fc2 = (const float*)d_in[11];
  const float* b_fc2 = (const float*)d_in[12];

  fused_lstm<<<dim3(8192 / BB), dim3(NTHREADS), 0, stream>>>(
      x, w_ih0, w_hh0, b_ih0, b_hh0, w_ih1, w_hh1, b_ih1, b_hh1,
      w_fc1, b_fc1, w_fc2, b_fc2, (float*)d_out);
}

// Round 5
// 401.232 us; speedup vs baseline: 13.1385x; 2.0990x over previous
//
#include <hip/hip_runtime.h>

// R5 = R4 with the LDS-pointer-array compile error fixed (offset arithmetic
// instead of arrays of __shared__ pointers).
// MFMA LSTM + native-exp2 activations (pre-scaled weights), 1 barrier/step
// via double-buffered h/x LDS, 2 blocks/CU (BB=16) for cross-block overlap.

#define TT 256
#define II 14
#define BB 16
#define NTHREADS 256
#define XP 40  // xs row pitch (halfs)
#define HP 72  // hbuf row pitch (halfs)
#define LOG2E 1.44269504088896340736f

typedef _Float16 f16x8 __attribute__((ext_vector_type(8)));
typedef _Float16 f16x4 __attribute__((ext_vector_type(4)));
typedef float f32x4 __attribute__((ext_vector_type(4)));

__device__ __forceinline__ f32x4 MFMA16(f16x8 a, f16x8 b, f32x4 c) {
  return __builtin_amdgcn_mfma_f32_16x16x32_f16(a, b, c, 0, 0, 0);
}

__device__ __forceinline__ float ex2(float x) {
#if __has_builtin(__builtin_amdgcn_exp2f)
  return __builtin_amdgcn_exp2f(x);
#else
  float r; asm("v_exp_f32 %0, %1" : "=v"(r) : "v"(x)); return r;
#endif
}
__device__ __forceinline__ float rcp_(float x) {
#if __has_builtin(__builtin_amdgcn_rcpf)
  return __builtin_amdgcn_rcpf(x);
#else
  float r; asm("v_rcp_f32 %0, %1" : "=v"(r) : "v"(x)); return r;
#endif
}
// with s = -log2e * preact : returns sigmoid(preact)
// with s = 2*log2e * preact: 1 - 2*gsig(s) = tanh(preact)
__device__ __forceinline__ float gsig(float s) { return rcp_(1.0f + ex2(s)); }

__global__ void __launch_bounds__(NTHREADS, 2) fused_lstm(
    const float* __restrict__ x,
    const float* __restrict__ w_ih0, const float* __restrict__ w_hh0,
    const float* __restrict__ b_ih0, const float* __restrict__ b_hh0,
    const float* __restrict__ w_ih1, const float* __restrict__ w_hh1,
    const float* __restrict__ b_ih1, const float* __restrict__ b_hh1,
    const float* __restrict__ w_fc1, const float* __restrict__ b_fc1,
    const float* __restrict__ w_fc2, const float* __restrict__ b_fc2,
    float* __restrict__ out) {
  // LDS bytes: hb1[2] @0 (2x2304) ; hb0[2] @4608 (2x2304) ; xs[2] @9216 (2x1280)
  __shared__ char smem[11776];

  const int tid = threadIdx.x;
  const int w = tid >> 6;    // wave: owns gate rows w*16..w*16+15 per gate type
  const int l = tid & 63;
  const int row16 = l & 15;  // A: M row / B: N col / C,D: N col
  const int kblk = l >> 4;   // A,B: k-block of 8 / C,D: row-block of 4
  const int b0 = blockIdx.x * BB;

  // ---- load weight A-fragments, pre-scaled: i,f,o rows *(-log2e); g rows *(2log2e) ----
  f16x8 a_ih0[4], a_hh0[4][2], a_ih1[4][2], a_hh1[4][2];
#pragma unroll
  for (int gt = 0; gt < 4; ++gt) {
    const float sc = (gt == 2) ? (2.0f * LOG2E) : (-LOG2E);
    const int g = gt * 64 + w * 16 + row16;
    {
      f16x8 v;
#pragma unroll
      for (int j = 0; j < 8; ++j) {
        const int k = kblk * 8 + j;  // K padded 14 -> 32
        v[j] = (k < II) ? (_Float16)(w_ih0[g * II + k] * sc) : (_Float16)0.0f;
      }
      a_ih0[gt] = v;
    }
#pragma unroll
    for (int ks = 0; ks < 2; ++ks) {
      const int ko = ks * 32 + kblk * 8;
      f16x8 v0, v1, v2;
#pragma unroll
      for (int j = 0; j < 8; ++j) v0[j] = (_Float16)(w_hh0[g * 64 + ko + j] * sc);
#pragma unroll
      for (int j = 0; j < 8; ++j) v1[j] = (_Float16)(w_ih1[g * 64 + ko + j] * sc);
#pragma unroll
      for (int j = 0; j < 8; ++j) v2[j] = (_Float16)(w_hh1[g * 64 + ko + j] * sc);
      a_hh0[gt][ks] = v0;
      a_ih1[gt][ks] = v1;
      a_hh1[gt][ks] = v2;
    }
  }
  f32x4 bias0[4], bias1[4];
#pragma unroll
  for (int gt = 0; gt < 4; ++gt) {
    const float sc = (gt == 2) ? (2.0f * LOG2E) : (-LOG2E);
#pragma unroll
    for (int r = 0; r < 4; ++r) {
      const int g = gt * 64 + w * 16 + kblk * 4 + r;  // C/D row mapping
      bias0[gt][r] = (b_ih0[g] + b_hh0[g]) * sc;
      bias1[gt][r] = (b_ih1[g] + b_hh1[g]) * sc;
    }
  }

  for (int i = tid; i < 11776 / 4; i += NTHREADS) ((int*)smem)[i] = 0;

  // x staging: BB*II = 224 slots, thread tid<224 owns one (row,k)
  const int n0 = tid / II, k0 = tid - n0 * II;
  const bool hasx = tid < BB * II;
  const float* xp0 = x + (size_t)(b0 + (hasx ? n0 : 0)) * (TT * II) + k0;

  __syncthreads();  // zeros done
  if (hasx) *((_Float16*)(smem + 9216) + n0 * XP + k0) = (_Float16)xp0[0];
  __syncthreads();  // x(0) staged

  f32x4 c0s = {0.f, 0.f, 0.f, 0.f}, c1s = {0.f, 0.f, 0.f, 0.f};

  for (int t = 0; t < TT; ++t) {
    const int cur = t & 1, prv = cur ^ 1;
    const _Float16* xs = (const _Float16*)(smem + 9216 + cur * 1280);
    _Float16* xs_n = (_Float16*)(smem + 9216 + prv * 1280);
    const _Float16* h0r = (const _Float16*)(smem + 4608 + prv * 2304);  // h0(t-1)
    _Float16* h0w = (_Float16*)(smem + 4608 + cur * 2304);
    const _Float16* h1r = (const _Float16*)(smem + prv * 2304);         // h1(t-1)
    _Float16* h1w = (_Float16*)(smem + cur * 2304);

    // ===== Phase A: layer-0 GEMM =====
    f32x4 acc[4];
#pragma unroll
    for (int gt = 0; gt < 4; ++gt) acc[gt] = bias0[gt];
    const f16x8 bx = *(const f16x8*)(xs + row16 * XP + kblk * 8);
    const f16x8 bh0a = *(const f16x8*)(h0r + row16 * HP + kblk * 8);
    const f16x8 bh0c = *(const f16x8*)(h0r + row16 * HP + 32 + kblk * 8);
#pragma unroll
    for (int gt = 0; gt < 4; ++gt) {
      acc[gt] = MFMA16(a_ih0[gt], bx, acc[gt]);
      acc[gt] = MFMA16(a_hh0[gt][0], bh0a, acc[gt]);
      acc[gt] = MFMA16(a_hh0[gt][1], bh0c, acc[gt]);
    }

    // prefetch x(t+1)
    float xn = 0.0f;
    if (hasx && t + 1 < TT) xn = xp0[(size_t)(t + 1) * II];

    // ===== layer-0 activations (pre-scaled: gsig is sigmoid directly) =====
    f16x4 h0p;
#pragma unroll
    for (int r = 0; r < 4; ++r) {
      const float ig = gsig(acc[0][r]);
      const float fg = gsig(acc[1][r]);
      const float gg = fmaf(-2.0f, gsig(acc[2][r]), 1.0f);
      const float og = gsig(acc[3][r]);
      const float c = fmaf(fg, c0s[r], ig * gg);
      c0s[r] = c;
      const float th = fmaf(-2.0f, gsig(2.0f * LOG2E * c), 1.0f);
      h0p[r] = (_Float16)(og * th);
    }

    // ===== Phase B: publish h0(t) -> hb0[cur], x(t+1) -> xs[prv] =====
    *(f16x4*)(h0w + row16 * HP + w * 16 + kblk * 4) = h0p;
    if (hasx && t + 1 < TT) xs_n[n0 * XP + k0] = (_Float16)xn;
    __syncthreads();  // the ONE barrier per timestep

    // ===== Phase C: layer-1 GEMM (input h0(t), recurrent h1(t-1)) =====
#pragma unroll
    for (int gt = 0; gt < 4; ++gt) acc[gt] = bias1[gt];
    const f16x8 bg0 = *(const f16x8*)(h0w + row16 * HP + kblk * 8);
    const f16x8 bg1 = *(const f16x8*)(h0w + row16 * HP + 32 + kblk * 8);
    const f16x8 bh1a = *(const f16x8*)(h1r + row16 * HP + kblk * 8);
    const f16x8 bh1c = *(const f16x8*)(h1r + row16 * HP + 32 + kblk * 8);
#pragma unroll
    for (int gt = 0; gt < 4; ++gt) {
      acc[gt] = MFMA16(a_ih1[gt][0], bg0, acc[gt]);
      acc[gt] = MFMA16(a_ih1[gt][1], bg1, acc[gt]);
      acc[gt] = MFMA16(a_hh1[gt][0], bh1a, acc[gt]);
      acc[gt] = MFMA16(a_hh1[gt][1], bh1c, acc[gt]);
    }

    // ===== layer-1 activations =====
    f16x4 h1p;
#pragma unroll
    for (int r = 0; r < 4; ++r) {
      const float ig = gsig(acc[0][r]);
      const float fg = gsig(acc[1][r]);
      const float gg = fmaf(-2.0f, gsig(acc[2][r]), 1.0f);
      const float og = gsig(acc[3][r]);
      const float c = fmaf(fg, c1s[r], ig * gg);
      c1s[r] = c;
      const float th = fmaf(-2.0f, gsig(2.0f * LOG2E * c), 1.0f);
      h1p[r] = (_Float16)(og * th);
    }

    // ===== Phase D: publish h1(t) -> hb1[cur] (no barrier; next A won't touch) =====
    *(f16x4*)(h1w + row16 * HP + w * 16 + kblk * 4) = h1p;
  }
  __syncthreads();  // final h1(255) visible (in buffer (TT-1)&1)

  // ===== FC head =====
  const _Float16* h1f = (const _Float16*)(smem + ((TT - 1) & 1) * 2304);
  float* zbuf = (float*)(smem + 4608);  // overlays hb0/xs (dead)
  float4 w1r[16];
#pragma unroll
  for (int k4 = 0; k4 < 16; ++k4) w1r[k4] = *(const float4*)(w_fc1 + l * 64 + k4 * 4);
  const float b1l = b_fc1[l];
#pragma unroll
  for (int bi = 0; bi < 4; ++bi) {
    const int n = w * 4 + bi;
    float s = b1l;
#pragma unroll
    for (int k4 = 0; k4 < 16; ++k4) {
      const float4 wv = w1r[k4];
      s = fmaf((float)h1f[n * HP + k4 * 4 + 0], wv.x, s);
      s = fmaf((float)h1f[n * HP + k4 * 4 + 1], wv.y, s);
      s = fmaf((float)h1f[n * HP + k4 * 4 + 2], wv.z, s);
      s = fmaf((float)h1f[n * HP + k4 * 4 + 3], wv.w, s);
    }
    zbuf[n * 64 + l] = fmaxf(s, 0.0f);
  }
  __syncthreads();
  if (tid < 2 * BB) {
    const int n = tid >> 1, cc = tid & 1;
    float s = b_fc2[cc];
    for (int j = 0; j < 64; ++j) s = fmaf(w_fc2[cc * 64 + j], zbuf[n * 64 + j], s);
    out[(size_t)(b0 + n) * 2 + cc] = s;
  }
}

extern "C" void kernel_launch(void* const* d_in, const int* in_sizes, int n_in,
                              void* d_out, int out_size, void* d_ws, size_t ws_size,
                              hipStream_t stream) {
  (void)in_sizes; (void)n_in; (void)d_ws; (void)ws_size; (void)out_size;
  const float* x = (const float*)d_in[0];
  const float* w_ih0 = (const float*)d_in[1];
  const float* w_hh0 = (const float*)d_in[2];
  const float* b_ih0 = (const float*)d_in[3];
  const float* b_hh0 = (const float*)d_in[4];
  const float* w_ih1 = (const float*)d_in[5];
  const float* w_hh1 = (const float*)d_in[6];
  const float* b_ih1 = (const float*)d_in[7];
  const float* b_hh1 = (const float*)d_in[8];
  const float* w_fc1 = (const float*)d_in[9];
  const float* b_fc1 = (const float*)d_in[10];
  const float* w_fc2 = (const float*)d_in[11];
  const float* b_fc2 = (const float*)d_in[12];

  fused_lstm<<<dim3(8192 / BB), dim3(NTHREADS), 0, stream>>>(
      x, w_ih0, w_hh0, b_ih0, b_hh0, w_ih1, w_hh1, b_ih1, b_hh1,
      w_fc1, b_fc1, w_fc2, b_fc2, (float*)d_out);
}

// Round 6
// 388.650 us; speedup vs baseline: 13.5639x; 1.0324x over previous
//
#include <hip/hip_runtime.h>

// R6: layer-skewed merged phases. Iteration t computes GEMM0(t) AND GEMM1(t-1)
// together (they share the h0(t-1) operand), then both activation blocks
// together -> one GEMM->act serial phase per step instead of two, one barrier.
// MFMA weights in VGPRs, native exp2/rcp activations with pre-scaled weights.

#define TT 256
#define II 14
#define BB 16
#define NTHREADS 256
#define XP 40  // xs row pitch (halfs)
#define HP 72  // hbuf row pitch (halfs)
#define LOG2E 1.44269504088896340736f

typedef _Float16 f16x8 __attribute__((ext_vector_type(8)));
typedef _Float16 f16x4 __attribute__((ext_vector_type(4)));
typedef float f32x4 __attribute__((ext_vector_type(4)));

__device__ __forceinline__ f32x4 MFMA16(f16x8 a, f16x8 b, f32x4 c) {
  return __builtin_amdgcn_mfma_f32_16x16x32_f16(a, b, c, 0, 0, 0);
}

__device__ __forceinline__ float ex2(float x) {
#if __has_builtin(__builtin_amdgcn_exp2f)
  return __builtin_amdgcn_exp2f(x);
#else
  float r; asm("v_exp_f32 %0, %1" : "=v"(r) : "v"(x)); return r;
#endif
}
__device__ __forceinline__ float rcp_(float x) {
#if __has_builtin(__builtin_amdgcn_rcpf)
  return __builtin_amdgcn_rcpf(x);
#else
  float r; asm("v_rcp_f32 %0, %1" : "=v"(r) : "v"(x)); return r;
#endif
}
// s = -log2e*preact -> sigmoid(preact);  s = 2log2e*preact -> (1-2*gsig) = tanh
__device__ __forceinline__ float gsig(float s) { return rcp_(1.0f + ex2(s)); }

// gates (pre-scaled) -> h (f16x4), updates c-state in place
__device__ __forceinline__ f16x4 lstm_act(f32x4 ai, f32x4 af, f32x4 ag, f32x4 ao,
                                          f32x4& cs) {
  f16x4 hp;
#pragma unroll
  for (int r = 0; r < 4; ++r) {
    const float ig = gsig(ai[r]);
    const float fg = gsig(af[r]);
    const float gg = fmaf(-2.0f, gsig(ag[r]), 1.0f);
    const float og = gsig(ao[r]);
    const float c = fmaf(fg, cs[r], ig * gg);
    cs[r] = c;
    const float th = fmaf(-2.0f, gsig(2.0f * LOG2E * c), 1.0f);
    hp[r] = (_Float16)(og * th);
  }
  return hp;
}

__global__ void __launch_bounds__(NTHREADS, 2) fused_lstm(
    const float* __restrict__ x,
    const float* __restrict__ w_ih0, const float* __restrict__ w_hh0,
    const float* __restrict__ b_ih0, const float* __restrict__ b_hh0,
    const float* __restrict__ w_ih1, const float* __restrict__ w_hh1,
    const float* __restrict__ b_ih1, const float* __restrict__ b_hh1,
    const float* __restrict__ w_fc1, const float* __restrict__ b_fc1,
    const float* __restrict__ w_fc2, const float* __restrict__ b_fc2,
    float* __restrict__ out) {
  // LDS bytes: H1[2] @0 (2x2304) ; H0[2] @4608 (2x2304) ; XS[2] @9216 (2x1280)
  __shared__ char smem[11776];

  const int tid = threadIdx.x;
  const int w = tid >> 6;
  const int l = tid & 63;
  const int row16 = l & 15;  // A: M row / B,C,D: N col (batch)
  const int kblk = l >> 4;   // A,B: k-block of 8 / C,D: row-block of 4
  const int b0 = blockIdx.x * BB;

  // ---- weight A-fragments, pre-scaled: i,f,o rows *(-log2e); g rows *(2log2e) ----
  f16x8 a_ih0[4], a_hh0[4][2], a_ih1[4][2], a_hh1[4][2];
#pragma unroll
  for (int gt = 0; gt < 4; ++gt) {
    const float sc = (gt == 2) ? (2.0f * LOG2E) : (-LOG2E);
    const int g = gt * 64 + w * 16 + row16;
    {
      f16x8 v;
#pragma unroll
      for (int j = 0; j < 8; ++j) {
        const int k = kblk * 8 + j;  // K padded 14 -> 32
        v[j] = (k < II) ? (_Float16)(w_ih0[g * II + k] * sc) : (_Float16)0.0f;
      }
      a_ih0[gt] = v;
    }
#pragma unroll
    for (int ks = 0; ks < 2; ++ks) {
      const int ko = ks * 32 + kblk * 8;
      f16x8 v0, v1, v2;
#pragma unroll
      for (int j = 0; j < 8; ++j) v0[j] = (_Float16)(w_hh0[g * 64 + ko + j] * sc);
#pragma unroll
      for (int j = 0; j < 8; ++j) v1[j] = (_Float16)(w_ih1[g * 64 + ko + j] * sc);
#pragma unroll
      for (int j = 0; j < 8; ++j) v2[j] = (_Float16)(w_hh1[g * 64 + ko + j] * sc);
      a_hh0[gt][ks] = v0;
      a_ih1[gt][ks] = v1;
      a_hh1[gt][ks] = v2;
    }
  }
  f32x4 bias0[4], bias1[4];
#pragma unroll
  for (int gt = 0; gt < 4; ++gt) {
    const float sc = (gt == 2) ? (2.0f * LOG2E) : (-LOG2E);
#pragma unroll
    for (int r = 0; r < 4; ++r) {
      const int g = gt * 64 + w * 16 + kblk * 4 + r;  // C/D row mapping
      bias0[gt][r] = (b_ih0[g] + b_hh0[g]) * sc;
      bias1[gt][r] = (b_ih1[g] + b_hh1[g]) * sc;
    }
  }

  for (int i = tid; i < 11776 / 4; i += NTHREADS) ((int*)smem)[i] = 0;

  // x staging: BB*II = 224 slots, thread tid<224 owns one (row,k)
  const int n0 = tid / II, k0 = tid - n0 * II;
  const bool hasx = tid < BB * II;
  const float* xp0 = x + (size_t)(b0 + (hasx ? n0 : 0)) * (TT * II) + k0;

  __syncthreads();  // zeros done
  if (hasx) *((_Float16*)(smem + 9216) + n0 * XP + k0) = (_Float16)xp0[0];
  __syncthreads();  // x(0) staged

  f32x4 c0s = {0.f, 0.f, 0.f, 0.f}, c1s = {0.f, 0.f, 0.f, 0.f};

  const int boff = row16 * HP + kblk * 8;          // B-frag byte offset (halfs)
  const int woff = row16 * HP + w * 16 + kblk * 4; // C/D publish offset (halfs)

  // ================= prologue: iteration t=0, layer-0 only =================
  {
    const _Float16* xs = (const _Float16*)(smem + 9216);          // XS(0)
    const _Float16* h0r = (const _Float16*)(smem + 4608 + 2304);  // H0(1)=zeros
    f32x4 acc0[4];
#pragma unroll
    for (int gt = 0; gt < 4; ++gt) acc0[gt] = bias0[gt];
    const f16x8 bx = *(const f16x8*)(xs + row16 * XP + kblk * 8);
    const f16x8 bh0a = *(const f16x8*)(h0r + boff);
    const f16x8 bh0c = *(const f16x8*)(h0r + 32 + boff);
#pragma unroll
    for (int gt = 0; gt < 4; ++gt) {
      acc0[gt] = MFMA16(a_ih0[gt], bx, acc0[gt]);
      acc0[gt] = MFMA16(a_hh0[gt][0], bh0a, acc0[gt]);
      acc0[gt] = MFMA16(a_hh0[gt][1], bh0c, acc0[gt]);
    }
    float xn = hasx ? xp0[II] : 0.0f;  // x(1)
    const f16x4 h0p = lstm_act(acc0[0], acc0[1], acc0[2], acc0[3], c0s);
    *(f16x4*)((_Float16*)(smem + 4608) + woff) = h0p;            // h0(0)->H0(0)
    if (hasx) *((_Float16*)(smem + 9216 + 1280) + n0 * XP + k0) = (_Float16)xn;
    __syncthreads();
  }

  // ================= main loop: t=1..TT-1 =================
  for (int t = 1; t < TT; ++t) {
    const int pc = t & 1, pp = pc ^ 1;
    const _Float16* xs = (const _Float16*)(smem + 9216 + pc * 1280);   // x(t)
    const _Float16* h0r = (const _Float16*)(smem + 4608 + pp * 2304);  // h0(t-1)
    const _Float16* h1r = (const _Float16*)(smem + pc * 2304);         // h1(t-2)
    _Float16* h0w = (_Float16*)(smem + 4608 + pc * 2304);              // h0(t)
    _Float16* h1w = (_Float16*)(smem + pp * 2304);                     // h1(t-1)
    _Float16* xsw = (_Float16*)(smem + 9216 + pp * 1280);              // x(t+1)

    // ---- merged GEMMs: L0(t) and L1(t-1), sharing bh0 ----
    const f16x8 bx = *(const f16x8*)(xs + row16 * XP + kblk * 8);
    const f16x8 bh0a = *(const f16x8*)(h0r + boff);
    const f16x8 bh0c = *(const f16x8*)(h0r + 32 + boff);
    const f16x8 bh1a = *(const f16x8*)(h1r + boff);
    const f16x8 bh1c = *(const f16x8*)(h1r + 32 + boff);
    f32x4 acc0[4], acc1[4];
#pragma unroll
    for (int gt = 0; gt < 4; ++gt) {
      acc0[gt] = bias0[gt];
      acc1[gt] = bias1[gt];
    }
#pragma unroll
    for (int gt = 0; gt < 4; ++gt) {
      acc0[gt] = MFMA16(a_ih0[gt], bx, acc0[gt]);
      acc0[gt] = MFMA16(a_hh0[gt][0], bh0a, acc0[gt]);
      acc0[gt] = MFMA16(a_hh0[gt][1], bh0c, acc0[gt]);
      acc1[gt] = MFMA16(a_ih1[gt][0], bh0a, acc1[gt]);
      acc1[gt] = MFMA16(a_ih1[gt][1], bh0c, acc1[gt]);
      acc1[gt] = MFMA16(a_hh1[gt][0], bh1a, acc1[gt]);
      acc1[gt] = MFMA16(a_hh1[gt][1], bh1c, acc1[gt]);
    }

    // prefetch x(t+1)
    float xn = 0.0f;
    if (hasx && t + 1 < TT) xn = xp0[(size_t)(t + 1) * II];

    // ---- merged activations (8 independent r-chains) ----
    const f16x4 h0p = lstm_act(acc0[0], acc0[1], acc0[2], acc0[3], c0s);
    const f16x4 h1p = lstm_act(acc1[0], acc1[1], acc1[2], acc1[3], c1s);

    // ---- publish + single barrier ----
    *(f16x4*)(h0w + woff) = h0p;
    *(f16x4*)(h1w + woff) = h1p;
    if (hasx && t + 1 < TT) xsw[n0 * XP + k0] = (_Float16)xn;
    __syncthreads();
  }

  // ================= epilogue: L1 step for t=TT-1 =================
  {
    const _Float16* h0r = (const _Float16*)(smem + 4608 + 2304);  // h0(TT-1), pp=1
    const _Float16* h1r = (const _Float16*)(smem);                // h1(TT-2), pc=0
    _Float16* h1w = (_Float16*)(smem + 2304);                     // h1(TT-1)
    f32x4 acc1[4];
#pragma unroll
    for (int gt = 0; gt < 4; ++gt) acc1[gt] = bias1[gt];
    const f16x8 bh0a = *(const f16x8*)(h0r + boff);
    const f16x8 bh0c = *(const f16x8*)(h0r + 32 + boff);
    const f16x8 bh1a = *(const f16x8*)(h1r + boff);
    const f16x8 bh1c = *(const f16x8*)(h1r + 32 + boff);
#pragma unroll
    for (int gt = 0; gt < 4; ++gt) {
      acc1[gt] = MFMA16(a_ih1[gt][0], bh0a, acc1[gt]);
      acc1[gt] = MFMA16(a_ih1[gt][1], bh0c, acc1[gt]);
      acc1[gt] = MFMA16(a_hh1[gt][0], bh1a, acc1[gt]);
      acc1[gt] = MFMA16(a_hh1[gt][1], bh1c, acc1[gt]);
    }
    const f16x4 h1p = lstm_act(acc1[0], acc1[1], acc1[2], acc1[3], c1s);
    *(f16x4*)(h1w + woff) = h1p;
    __syncthreads();
  }

  // ================= FC head =================
  const _Float16* h1f = (const _Float16*)(smem + 2304);  // h1(TT-1)
  float* zbuf = (float*)(smem + 4608);                   // overlays H0 (dead)
  float4 w1r[16];
#pragma unroll
  for (int k4 = 0; k4 < 16; ++k4) w1r[k4] = *(const float4*)(w_fc1 + l * 64 + k4 * 4);
  const float b1l = b_fc1[l];
#pragma unroll
  for (int bi = 0; bi < 4; ++bi) {
    const int n = w * 4 + bi;
    float s = b1l;
#pragma unroll
    for (int k4 = 0; k4 < 16; ++k4) {
      const float4 wv = w1r[k4];
      s = fmaf((float)h1f[n * HP + k4 * 4 + 0], wv.x, s);
      s = fmaf((float)h1f[n * HP + k4 * 4 + 1], wv.y, s);
      s = fmaf((float)h1f[n * HP + k4 * 4 + 2], wv.z, s);
      s = fmaf((float)h1f[n * HP + k4 * 4 + 3], wv.w, s);
    }
    zbuf[n * 64 + l] = fmaxf(s, 0.0f);
  }
  __syncthreads();
  if (tid < 2 * BB) {
    const int n = tid >> 1, cc = tid & 1;
    float s = b_fc2[cc];
    for (int j = 0; j < 64; ++j) s = fmaf(w_fc2[cc * 64 + j], zbuf[n * 64 + j], s);
    out[(size_t)(b0 + n) * 2 + cc] = s;
  }
}

extern "C" void kernel_launch(void* const* d_in, const int* in_sizes, int n_in,
                              void* d_out, int out_size, void* d_ws, size_t ws_size,
                              hipStream_t stream) {
  (void)in_sizes; (void)n_in; (void)d_ws; (void)ws_size; (void)out_size;
  const float* x = (const float*)d_in[0];
  const float* w_ih0 = (const float*)d_in[1];
  const float* w_hh0 = (const float*)d_in[2];
  const float* b_ih0 = (const float*)d_in[3];
  const float* b_hh0 = (const float*)d_in[4];
  const float* w_ih1 = (const float*)d_in[5];
  const float* w_hh1 = (const float*)d_in[6];
  const float* b_ih1 = (const float*)d_in[7];
  const float* b_hh1 = (const float*)d_in[8];
  const float* w_fc1 = (const float*)d_in[9];
  const float* b_fc1 = (const float*)d_in[10];
  const float* w_fc2 = (const float*)d_in[11];
  const float* b_fc2 = (const float*)d_in[12];

  fused_lstm<<<dim3(8192 / BB), dim3(NTHREADS), 0, stream>>>(
      x, w_ih0, w_hh0, b_ih0, b_hh0, w_ih1, w_hh1, b_ih1, b_hh1,
      w_fc1, b_fc1, w_fc2, b_fc2, (float*)d_out);
}

// Round 7
// 360.623 us; speedup vs baseline: 14.6180x; 1.0777x over previous
//
#include <hip/hip_runtime.h>

// R7 = R6 + rational-form LSTM activations: one shared rcp per c-update and
// per h-output (7 trans/output vs 10). exp2-domain via pre-scaled weights.
// Layer-skewed merged GEMMs, 1 barrier/step, weights in VGPRs, 2 blocks/CU.

#define TT 256
#define II 14
#define BB 16
#define NTHREADS 256
#define XP 40  // xs row pitch (halfs)
#define HP 72  // hbuf row pitch (halfs)
#define LOG2E 1.44269504088896340736f

typedef _Float16 f16x8 __attribute__((ext_vector_type(8)));
typedef _Float16 f16x4 __attribute__((ext_vector_type(4)));
typedef float f32x4 __attribute__((ext_vector_type(4)));

__device__ __forceinline__ f32x4 MFMA16(f16x8 a, f16x8 b, f32x4 c) {
  return __builtin_amdgcn_mfma_f32_16x16x32_f16(a, b, c, 0, 0, 0);
}

__device__ __forceinline__ float ex2(float x) {
#if __has_builtin(__builtin_amdgcn_exp2f)
  return __builtin_amdgcn_exp2f(x);
#else
  float r; asm("v_exp_f32 %0, %1" : "=v"(r) : "v"(x)); return r;
#endif
}
__device__ __forceinline__ float rcp_(float x) {
#if __has_builtin(__builtin_amdgcn_rcpf)
  return __builtin_amdgcn_rcpf(x);
#else
  float r; asm("v_rcp_f32 %0, %1" : "=v"(r) : "v"(x)); return r;
#endif
}

// Pre-scaled gate inputs: s_i=-log2e*a_i, s_f=-log2e*a_f, s_g=+2log2e*a_g,
// s_o=-log2e*a_o. With u=2^s:
//   sigmoid(a_i)=1/(1+u_i), tanh(a_g)=(u_g-1)/(u_g+1)
//   c' = [c*(1+u_i)(1+u_g) + (u_g-1)(1+u_f)] / [(1+u_f)(1+u_i)(1+u_g)]
//   h  = sigmoid(a_o)*tanh(c') = (u_t-1)/[(1+u_o)(1+u_t)],  u_t=2^(2log2e*c')
__device__ __forceinline__ f16x4 lstm_act(f32x4 si, f32x4 sf, f32x4 sg, f32x4 so,
                                          f32x4& cs) {
  f16x4 hp;
#pragma unroll
  for (int r = 0; r < 4; ++r) {
    const float ui = ex2(si[r]);
    const float uf = ex2(sf[r]);
    const float ug = ex2(sg[r]);
    const float uo = ex2(so[r]);
    const float fi = 1.0f + ui;
    const float ff = 1.0f + uf;
    const float fg = 1.0f + ug;
    const float pig = fi * fg;
    const float num = fmaf(cs[r], pig, (ug - 1.0f) * ff);
    const float c = num * rcp_(pig * ff);
    cs[r] = c;
    const float ut = ex2(2.0f * LOG2E * c);
    const float h = (ut - 1.0f) * rcp_((1.0f + uo) * (1.0f + ut));
    hp[r] = (_Float16)h;
  }
  return hp;
}

__global__ void __launch_bounds__(NTHREADS, 2) fused_lstm(
    const float* __restrict__ x,
    const float* __restrict__ w_ih0, const float* __restrict__ w_hh0,
    const float* __restrict__ b_ih0, const float* __restrict__ b_hh0,
    const float* __restrict__ w_ih1, const float* __restrict__ w_hh1,
    const float* __restrict__ b_ih1, const float* __restrict__ b_hh1,
    const float* __restrict__ w_fc1, const float* __restrict__ b_fc1,
    const float* __restrict__ w_fc2, const float* __restrict__ b_fc2,
    float* __restrict__ out) {
  // LDS bytes: H1[2] @0 (2x2304) ; H0[2] @4608 (2x2304) ; XS[2] @9216 (2x1280)
  __shared__ char smem[11776];

  const int tid = threadIdx.x;
  const int w = tid >> 6;
  const int l = tid & 63;
  const int row16 = l & 15;  // A: M row / B,C,D: N col (batch)
  const int kblk = l >> 4;   // A,B: k-block of 8 / C,D: row-block of 4
  const int b0 = blockIdx.x * BB;

  // ---- weight A-fragments, pre-scaled: i,f,o rows *(-log2e); g rows *(2log2e) ----
  f16x8 a_ih0[4], a_hh0[4][2], a_ih1[4][2], a_hh1[4][2];
#pragma unroll
  for (int gt = 0; gt < 4; ++gt) {
    const float sc = (gt == 2) ? (2.0f * LOG2E) : (-LOG2E);
    const int g = gt * 64 + w * 16 + row16;
    {
      f16x8 v;
#pragma unroll
      for (int j = 0; j < 8; ++j) {
        const int k = kblk * 8 + j;  // K padded 14 -> 32
        v[j] = (k < II) ? (_Float16)(w_ih0[g * II + k] * sc) : (_Float16)0.0f;
      }
      a_ih0[gt] = v;
    }
#pragma unroll
    for (int ks = 0; ks < 2; ++ks) {
      const int ko = ks * 32 + kblk * 8;
      f16x8 v0, v1, v2;
#pragma unroll
      for (int j = 0; j < 8; ++j) v0[j] = (_Float16)(w_hh0[g * 64 + ko + j] * sc);
#pragma unroll
      for (int j = 0; j < 8; ++j) v1[j] = (_Float16)(w_ih1[g * 64 + ko + j] * sc);
#pragma unroll
      for (int j = 0; j < 8; ++j) v2[j] = (_Float16)(w_hh1[g * 64 + ko + j] * sc);
      a_hh0[gt][ks] = v0;
      a_ih1[gt][ks] = v1;
      a_hh1[gt][ks] = v2;
    }
  }
  f32x4 bias0[4], bias1[4];
#pragma unroll
  for (int gt = 0; gt < 4; ++gt) {
    const float sc = (gt == 2) ? (2.0f * LOG2E) : (-LOG2E);
#pragma unroll
    for (int r = 0; r < 4; ++r) {
      const int g = gt * 64 + w * 16 + kblk * 4 + r;  // C/D row mapping
      bias0[gt][r] = (b_ih0[g] + b_hh0[g]) * sc;
      bias1[gt][r] = (b_ih1[g] + b_hh1[g]) * sc;
    }
  }

  for (int i = tid; i < 11776 / 4; i += NTHREADS) ((int*)smem)[i] = 0;

  // x staging: BB*II = 224 slots, thread tid<224 owns one (row,k)
  const int n0 = tid / II, k0 = tid - n0 * II;
  const bool hasx = tid < BB * II;
  const float* xp0 = x + (size_t)(b0 + (hasx ? n0 : 0)) * (TT * II) + k0;

  __syncthreads();  // zeros done
  if (hasx) *((_Float16*)(smem + 9216) + n0 * XP + k0) = (_Float16)xp0[0];
  __syncthreads();  // x(0) staged

  f32x4 c0s = {0.f, 0.f, 0.f, 0.f}, c1s = {0.f, 0.f, 0.f, 0.f};

  const int boff = row16 * HP + kblk * 8;          // B-frag offset (halfs)
  const int woff = row16 * HP + w * 16 + kblk * 4; // C/D publish offset (halfs)

  // ================= prologue: iteration t=0, layer-0 only =================
  {
    const _Float16* xs = (const _Float16*)(smem + 9216);          // XS(0)
    const _Float16* h0r = (const _Float16*)(smem + 4608 + 2304);  // H0(1)=zeros
    f32x4 acc0[4];
#pragma unroll
    for (int gt = 0; gt < 4; ++gt) acc0[gt] = bias0[gt];
    const f16x8 bx = *(const f16x8*)(xs + row16 * XP + kblk * 8);
    const f16x8 bh0a = *(const f16x8*)(h0r + boff);
    const f16x8 bh0c = *(const f16x8*)(h0r + 32 + boff);
#pragma unroll
    for (int gt = 0; gt < 4; ++gt) {
      acc0[gt] = MFMA16(a_ih0[gt], bx, acc0[gt]);
      acc0[gt] = MFMA16(a_hh0[gt][0], bh0a, acc0[gt]);
      acc0[gt] = MFMA16(a_hh0[gt][1], bh0c, acc0[gt]);
    }
    float xn = hasx ? xp0[II] : 0.0f;  // x(1)
    const f16x4 h0p = lstm_act(acc0[0], acc0[1], acc0[2], acc0[3], c0s);
    *(f16x4*)((_Float16*)(smem + 4608) + woff) = h0p;            // h0(0)->H0(0)
    if (hasx) *((_Float16*)(smem + 9216 + 1280) + n0 * XP + k0) = (_Float16)xn;
    __syncthreads();
  }

  // ================= main loop: t=1..TT-1 =================
#pragma unroll 2
  for (int t = 1; t < TT; ++t) {
    const int pc = t & 1, pp = pc ^ 1;
    const _Float16* xs = (const _Float16*)(smem + 9216 + pc * 1280);   // x(t)
    const _Float16* h0r = (const _Float16*)(smem + 4608 + pp * 2304);  // h0(t-1)
    const _Float16* h1r = (const _Float16*)(smem + pc * 2304);         // h1(t-2)
    _Float16* h0w = (_Float16*)(smem + 4608 + pc * 2304);              // h0(t)
    _Float16* h1w = (_Float16*)(smem + pp * 2304);                     // h1(t-1)
    _Float16* xsw = (_Float16*)(smem + 9216 + pp * 1280);              // x(t+1)

    // ---- merged GEMMs: L0(t) and L1(t-1), sharing bh0 ----
    const f16x8 bx = *(const f16x8*)(xs + row16 * XP + kblk * 8);
    const f16x8 bh0a = *(const f16x8*)(h0r + boff);
    const f16x8 bh0c = *(const f16x8*)(h0r + 32 + boff);
    const f16x8 bh1a = *(const f16x8*)(h1r + boff);
    const f16x8 bh1c = *(const f16x8*)(h1r + 32 + boff);
    f32x4 acc0[4], acc1[4];
#pragma unroll
    for (int gt = 0; gt < 4; ++gt) {
      acc0[gt] = bias0[gt];
      acc1[gt] = bias1[gt];
    }
#pragma unroll
    for (int gt = 0; gt < 4; ++gt) {
      acc0[gt] = MFMA16(a_ih0[gt], bx, acc0[gt]);
      acc0[gt] = MFMA16(a_hh0[gt][0], bh0a, acc0[gt]);
      acc0[gt] = MFMA16(a_hh0[gt][1], bh0c, acc0[gt]);
      acc1[gt] = MFMA16(a_ih1[gt][0], bh0a, acc1[gt]);
      acc1[gt] = MFMA16(a_ih1[gt][1], bh0c, acc1[gt]);
      acc1[gt] = MFMA16(a_hh1[gt][0], bh1a, acc1[gt]);
      acc1[gt] = MFMA16(a_hh1[gt][1], bh1c, acc1[gt]);
    }

    // prefetch x(t+1)
    float xn = 0.0f;
    if (hasx && t + 1 < TT) xn = xp0[(size_t)(t + 1) * II];

    // ---- merged activations (8 independent r-chains) ----
    const f16x4 h0p = lstm_act(acc0[0], acc0[1], acc0[2], acc0[3], c0s);
    const f16x4 h1p = lstm_act(acc1[0], acc1[1], acc1[2], acc1[3], c1s);

    // ---- publish + single barrier ----
    *(f16x4*)(h0w + woff) = h0p;
    *(f16x4*)(h1w + woff) = h1p;
    if (hasx && t + 1 < TT) xsw[n0 * XP + k0] = (_Float16)xn;
    __syncthreads();
  }

  // ================= epilogue: L1 step for t=TT-1 =================
  {
    const _Float16* h0r = (const _Float16*)(smem + 4608 + 2304);  // h0(TT-1), pp=1
    const _Float16* h1r = (const _Float16*)(smem);                // h1(TT-2), pc=0
    _Float16* h1w = (_Float16*)(smem + 2304);                     // h1(TT-1)
    f32x4 acc1[4];
#pragma unroll
    for (int gt = 0; gt < 4; ++gt) acc1[gt] = bias1[gt];
    const f16x8 bh0a = *(const f16x8*)(h0r + boff);
    const f16x8 bh0c = *(const f16x8*)(h0r + 32 + boff);
    const f16x8 bh1a = *(const f16x8*)(h1r + boff);
    const f16x8 bh1c = *(const f16x8*)(h1r + 32 + boff);
#pragma unroll
    for (int gt = 0; gt < 4; ++gt) {
      acc1[gt] = MFMA16(a_ih1[gt][0], bh0a, acc1[gt]);
      acc1[gt] = MFMA16(a_ih1[gt][1], bh0c, acc1[gt]);
      acc1[gt] = MFMA16(a_hh1[gt][0], bh1a, acc1[gt]);
      acc1[gt] = MFMA16(a_hh1[gt][1], bh1c, acc1[gt]);
    }
    const f16x4 h1p = lstm_act(acc1[0], acc1[1], acc1[2], acc1[3], c1s);
    *(f16x4*)(h1w + woff) = h1p;
    __syncthreads();
  }

  // ================= FC head =================
  const _Float16* h1f = (const _Float16*)(smem + 2304);  // h1(TT-1)
  float* zbuf = (float*)(smem + 4608);                   // overlays H0 (dead)
  float4 w1r[16];
#pragma unroll
  for (int k4 = 0; k4 < 16; ++k4) w1r[k4] = *(const float4*)(w_fc1 + l * 64 + k4 * 4);
  const float b1l = b_fc1[l];
#pragma unroll
  for (int bi = 0; bi < 4; ++bi) {
    const int n = w * 4 + bi;
    float s = b1l;
#pragma unroll
    for (int k4 = 0; k4 < 16; ++k4) {
      const float4 wv = w1r[k4];
      s = fmaf((float)h1f[n * HP + k4 * 4 + 0], wv.x, s);
      s = fmaf((float)h1f[n * HP + k4 * 4 + 1], wv.y, s);
      s = fmaf((float)h1f[n * HP + k4 * 4 + 2], wv.z, s);
      s = fmaf((float)h1f[n * HP + k4 * 4 + 3], wv.w, s);
    }
    zbuf[n * 64 + l] = fmaxf(s, 0.0f);
  }
  __syncthreads();
  if (tid < 2 * BB) {
    const int n = tid >> 1, cc = tid & 1;
    float s = b_fc2[cc];
    for (int j = 0; j < 64; ++j) s = fmaf(w_fc2[cc * 64 + j], zbuf[n * 64 + j], s);
    out[(size_t)(b0 + n) * 2 + cc] = s;
  }
}

extern "C" void kernel_launch(void* const* d_in, const int* in_sizes, int n_in,
                              void* d_out, int out_size, void* d_ws, size_t ws_size,
                              hipStream_t stream) {
  (void)in_sizes; (void)n_in; (void)d_ws; (void)ws_size; (void)out_size;
  const float* x = (const float*)d_in[0];
  const float* w_ih0 = (const float*)d_in[1];
  const float* w_hh0 = (const float*)d_in[2];
  const float* b_ih0 = (const float*)d_in[3];
  const float* b_hh0 = (const float*)d_in[4];
  const float* w_ih1 = (const float*)d_in[5];
  const float* w_hh1 = (const float*)d_in[6];
  const float* b_ih1 = (const float*)d_in[7];
  const float* b_hh1 = (const float*)d_in[8];
  const float* w_fc1 = (const float*)d_in[9];
  const float* b_fc1 = (const float*)d_in[10];
  const float* w_fc2 = (const float*)d_in[11];
  const float* b_fc2 = (const float*)d_in[12];

  fused_lstm<<<dim3(8192 / BB), dim3(NTHREADS), 0, stream>>>(
      x, w_ih0, w_hh0, b_ih0, b_hh0, w_ih1, w_hh1, b_ih1, b_hh1,
      w_fc1, b_fc1, w_fc2, b_fc2, (float*)d_out);
}

// Round 8
// 337.541 us; speedup vs baseline: 15.6176x; 1.0684x over previous
//
#include <hip/hip_runtime.h>

// R8: layer-split wave groups. 8-wave block (512 thr), BB=16: waves 0-3 run
// layer-0(t), waves 4-7 run layer-1(t-1) concurrently (R6/R7 layer skew),
// one barrier/step. 2 blocks/CU -> 4 waves/SIMD (2x R7) with per-wave work
// halved -> fills dependency stalls. Rational 7-trans activations (R7).

#define TT 256
#define II 14
#define BB 16
#define NTHREADS 512
#define XP 40  // xs row pitch (halfs)
#define HP 72  // hbuf row pitch (halfs)
#define LOG2E 1.44269504088896340736f

typedef _Float16 f16x8 __attribute__((ext_vector_type(8)));
typedef _Float16 f16x4 __attribute__((ext_vector_type(4)));
typedef float f32x4 __attribute__((ext_vector_type(4)));

__device__ __forceinline__ f32x4 MFMA16(f16x8 a, f16x8 b, f32x4 c) {
  return __builtin_amdgcn_mfma_f32_16x16x32_f16(a, b, c, 0, 0, 0);
}

__device__ __forceinline__ float ex2(float x) {
#if __has_builtin(__builtin_amdgcn_exp2f)
  return __builtin_amdgcn_exp2f(x);
#else
  float r; asm("v_exp_f32 %0, %1" : "=v"(r) : "v"(x)); return r;
#endif
}
__device__ __forceinline__ float rcp_(float x) {
#if __has_builtin(__builtin_amdgcn_rcpf)
  return __builtin_amdgcn_rcpf(x);
#else
  float r; asm("v_rcp_f32 %0, %1" : "=v"(r) : "v"(x)); return r;
#endif
}

// Pre-scaled gates (i,f,o: *-log2e ; g: *2log2e), u = 2^s:
//   c' = [c*(1+u_i)(1+u_g) + (u_g-1)(1+u_f)] / [(1+u_f)(1+u_i)(1+u_g)]
//   h  = (u_t-1)/[(1+u_o)(1+u_t)], u_t = 2^(2log2e*c')
__device__ __forceinline__ f16x4 lstm_act(f32x4 si, f32x4 sf, f32x4 sg, f32x4 so,
                                          f32x4& cs) {
  f16x4 hp;
#pragma unroll
  for (int r = 0; r < 4; ++r) {
    const float ui = ex2(si[r]);
    const float uf = ex2(sf[r]);
    const float ug = ex2(sg[r]);
    const float uo = ex2(so[r]);
    const float fi = 1.0f + ui;
    const float ff = 1.0f + uf;
    const float fg = 1.0f + ug;
    const float pig = fi * fg;
    const float num = fmaf(cs[r], pig, (ug - 1.0f) * ff);
    const float c = num * rcp_(pig * ff);
    cs[r] = c;
    const float ut = ex2(2.0f * LOG2E * c);
    const float h = (ut - 1.0f) * rcp_((1.0f + uo) * (1.0f + ut));
    hp[r] = (_Float16)h;
  }
  return hp;
}

__global__ void __launch_bounds__(NTHREADS, 4) fused_lstm(
    const float* __restrict__ x,
    const float* __restrict__ w_ih0, const float* __restrict__ w_hh0,
    const float* __restrict__ b_ih0, const float* __restrict__ b_hh0,
    const float* __restrict__ w_ih1, const float* __restrict__ w_hh1,
    const float* __restrict__ b_ih1, const float* __restrict__ b_hh1,
    const float* __restrict__ w_fc1, const float* __restrict__ b_fc1,
    const float* __restrict__ w_fc2, const float* __restrict__ b_fc2,
    float* __restrict__ out) {
  // LDS bytes: H1[2] @0 (2x2304) ; H0[2] @4608 (2x2304) ; XS[2] @9216 (2x1280)
  __shared__ char smem[11776];

  const int tid = threadIdx.x;
  const int wv = tid >> 6;
  const int grp = wv >> 2;   // 0: layer-0 waves, 1: layer-1 waves
  const int wl = wv & 3;     // hidden-tile index (16 units)
  const int l = tid & 63;
  const int row16 = l & 15;  // A: M row / B,C,D: N col (batch)
  const int kblk = l >> 4;   // A,B: k-block of 8 / C,D: row-block of 4

  const int b0 = blockIdx.x * BB;

  // ---- per-group weight A-fragments (one layer only), pre-scaled ----
  // grp0: wIn[gt][0] = w_ih0 frag (K=14 padded to 32), wIn[gt][1] unused;
  //       wRec = w_hh0.   grp1: wIn = w_ih1 (2 K-halves), wRec = w_hh1.
  f16x8 wIn[4][2], wRec[4][2];
  f32x4 bias[4];
#pragma unroll
  for (int gt = 0; gt < 4; ++gt) {
    const float sc = (gt == 2) ? (2.0f * LOG2E) : (-LOG2E);
    const int g = gt * 64 + wl * 16 + row16;
    if (grp == 0) {
      f16x8 v;
#pragma unroll
      for (int j = 0; j < 8; ++j) {
        const int k = kblk * 8 + j;
        v[j] = (k < II) ? (_Float16)(w_ih0[g * II + k] * sc) : (_Float16)0.0f;
      }
      wIn[gt][0] = v;
#pragma unroll
      for (int ks = 0; ks < 2; ++ks) {
        const int ko = ks * 32 + kblk * 8;
        f16x8 vr;
#pragma unroll
        for (int j = 0; j < 8; ++j) vr[j] = (_Float16)(w_hh0[g * 64 + ko + j] * sc);
        wRec[gt][ks] = vr;
      }
    } else {
#pragma unroll
      for (int ks = 0; ks < 2; ++ks) {
        const int ko = ks * 32 + kblk * 8;
        f16x8 vi, vr;
#pragma unroll
        for (int j = 0; j < 8; ++j) vi[j] = (_Float16)(w_ih1[g * 64 + ko + j] * sc);
#pragma unroll
        for (int j = 0; j < 8; ++j) vr[j] = (_Float16)(w_hh1[g * 64 + ko + j] * sc);
        wIn[gt][ks] = vi;
        wRec[gt][ks] = vr;
      }
    }
    const int gb = gt * 64 + wl * 16 + kblk * 4;  // C/D row base
#pragma unroll
    for (int r = 0; r < 4; ++r) {
      bias[gt][r] = (grp == 0) ? (b_ih0[gb + r] + b_hh0[gb + r]) * sc
                               : (b_ih1[gb + r] + b_hh1[gb + r]) * sc;
    }
  }

  for (int i = tid; i < 11776 / 4; i += NTHREADS) ((int*)smem)[i] = 0;

  // x staging: BB*II = 224 slots (all within grp0's waves)
  const int n0 = tid / II, k0 = tid - n0 * II;
  const bool hasx = tid < BB * II;
  const float* xp0 = x + (size_t)(b0 + (hasx ? n0 : 0)) * (TT * II) + k0;

  _Float16* H1 = (_Float16*)smem;            // [2][1152]
  _Float16* H0 = (_Float16*)(smem + 4608);   // [2][1152]
  _Float16* XS = (_Float16*)(smem + 9216);   // [2][640]

  __syncthreads();  // zeros done
  if (hasx) XS[n0 * XP + k0] = (_Float16)xp0[0];
  __syncthreads();  // x(0) staged

  f32x4 cs = {0.f, 0.f, 0.f, 0.f};

  const int boff = row16 * HP + kblk * 8;           // B-frag offset (halfs)
  const int woff = row16 * HP + wl * 16 + kblk * 4; // C/D publish offset

  // ============ prologue t=0: grp0 computes h0(0); grp1 idles ============
  if (grp == 0) {
    f32x4 acc[4];
#pragma unroll
    for (int gt = 0; gt < 4; ++gt) acc[gt] = bias[gt];
    const f16x8 bx = *(const f16x8*)(XS + row16 * XP + kblk * 8);
    const f16x8 bhA = *(const f16x8*)(H0 + 1152 + boff);      // zeros
    const f16x8 bhB = *(const f16x8*)(H0 + 1152 + 32 + boff);
#pragma unroll
    for (int gt = 0; gt < 4; ++gt) {
      acc[gt] = MFMA16(wIn[gt][0], bx, acc[gt]);
      acc[gt] = MFMA16(wRec[gt][0], bhA, acc[gt]);
      acc[gt] = MFMA16(wRec[gt][1], bhB, acc[gt]);
    }
    const float xn = hasx ? (float)xp0[II] : 0.0f;  // x(1)
    const f16x4 hp = lstm_act(acc[0], acc[1], acc[2], acc[3], cs);
    *(f16x4*)(H0 + woff) = hp;  // H0[0]
    if (hasx) XS[640 + n0 * XP + k0] = (_Float16)xn;
  }
  __syncthreads();

  // ============ main loop t=1..TT-1: grp0 does L0(t), grp1 does L1(t-1) ====
#pragma unroll 2
  for (int t = 1; t < TT; ++t) {
    const int pc = t & 1, pp = pc ^ 1;
    if (grp == 0) {
      f32x4 acc[4];
#pragma unroll
      for (int gt = 0; gt < 4; ++gt) acc[gt] = bias[gt];
      const f16x8 bx = *(const f16x8*)(XS + pc * 640 + row16 * XP + kblk * 8);
      const f16x8 bhA = *(const f16x8*)(H0 + pp * 1152 + boff);
      const f16x8 bhB = *(const f16x8*)(H0 + pp * 1152 + 32 + boff);
#pragma unroll
      for (int gt = 0; gt < 4; ++gt) {
        acc[gt] = MFMA16(wIn[gt][0], bx, acc[gt]);
        acc[gt] = MFMA16(wRec[gt][0], bhA, acc[gt]);
        acc[gt] = MFMA16(wRec[gt][1], bhB, acc[gt]);
      }
      float xn = 0.0f;
      if (hasx && t + 1 < TT) xn = xp0[(size_t)(t + 1) * II];
      const f16x4 hp = lstm_act(acc[0], acc[1], acc[2], acc[3], cs);
      *(f16x4*)(H0 + pc * 1152 + woff) = hp;  // h0(t)
      if (hasx && t + 1 < TT) XS[pp * 640 + n0 * XP + k0] = (_Float16)xn;
    } else {
      f32x4 acc[4];
#pragma unroll
      for (int gt = 0; gt < 4; ++gt) acc[gt] = bias[gt];
      const f16x8 bgA = *(const f16x8*)(H0 + pp * 1152 + boff);        // h0(t-1)
      const f16x8 bgB = *(const f16x8*)(H0 + pp * 1152 + 32 + boff);
      const f16x8 bhA = *(const f16x8*)(H1 + pc * 1152 + boff);        // h1(t-2)
      const f16x8 bhB = *(const f16x8*)(H1 + pc * 1152 + 32 + boff);
#pragma unroll
      for (int gt = 0; gt < 4; ++gt) {
        acc[gt] = MFMA16(wIn[gt][0], bgA, acc[gt]);
        acc[gt] = MFMA16(wIn[gt][1], bgB, acc[gt]);
        acc[gt] = MFMA16(wRec[gt][0], bhA, acc[gt]);
        acc[gt] = MFMA16(wRec[gt][1], bhB, acc[gt]);
      }
      const f16x4 hp = lstm_act(acc[0], acc[1], acc[2], acc[3], cs);
      *(f16x4*)(H1 + pp * 1152 + woff) = hp;  // h1(t-1)
    }
    __syncthreads();
  }

  // ============ epilogue t=TT: grp1 computes h1(TT-1) ============
  if (grp == 1) {  // pc=0, pp=1
    f32x4 acc[4];
#pragma unroll
    for (int gt = 0; gt < 4; ++gt) acc[gt] = bias[gt];
    const f16x8 bgA = *(const f16x8*)(H0 + 1152 + boff);  // h0(TT-1)
    const f16x8 bgB = *(const f16x8*)(H0 + 1152 + 32 + boff);
    const f16x8 bhA = *(const f16x8*)(H1 + boff);          // h1(TT-2)
    const f16x8 bhB = *(const f16x8*)(H1 + 32 + boff);
#pragma unroll
    for (int gt = 0; gt < 4; ++gt) {
      acc[gt] = MFMA16(wIn[gt][0], bgA, acc[gt]);
      acc[gt] = MFMA16(wIn[gt][1], bgB, acc[gt]);
      acc[gt] = MFMA16(wRec[gt][0], bhA, acc[gt]);
      acc[gt] = MFMA16(wRec[gt][1], bhB, acc[gt]);
    }
    const f16x4 hp = lstm_act(acc[0], acc[1], acc[2], acc[3], cs);
    *(f16x4*)(H1 + 1152 + woff) = hp;  // h1(TT-1)
  }
  __syncthreads();

  // ============ FC head (512 threads) ============
  const _Float16* h1f = (const _Float16*)(smem + 2304);  // H1[1]
  float* zbuf = (float*)(smem + 4608);                   // overlays H0 (dead)
  {
    float4 w1r[16];
#pragma unroll
    for (int k4 = 0; k4 < 16; ++k4)
      w1r[k4] = *(const float4*)(w_fc1 + l * 64 + k4 * 4);
    const float b1l = b_fc1[l];
#pragma unroll
    for (int bi = 0; bi < 2; ++bi) {
      const int n = wv * 2 + bi;
      float s = b1l;
#pragma unroll
      for (int k4 = 0; k4 < 16; ++k4) {
        const float4 wq = w1r[k4];
        s = fmaf((float)h1f[n * HP + k4 * 4 + 0], wq.x, s);
        s = fmaf((float)h1f[n * HP + k4 * 4 + 1], wq.y, s);
        s = fmaf((float)h1f[n * HP + k4 * 4 + 2], wq.z, s);
        s = fmaf((float)h1f[n * HP + k4 * 4 + 3], wq.w, s);
      }
      zbuf[n * 64 + l] = fmaxf(s, 0.0f);
    }
  }
  __syncthreads();
  if (tid < 2 * BB) {
    const int n = tid >> 1, cc = tid & 1;
    float s = b_fc2[cc];
    for (int j = 0; j < 64; ++j) s = fmaf(w_fc2[cc * 64 + j], zbuf[n * 64 + j], s);
    out[(size_t)(b0 + n) * 2 + cc] = s;
  }
}

extern "C" void kernel_launch(void* const* d_in, const int* in_sizes, int n_in,
                              void* d_out, int out_size, void* d_ws, size_t ws_size,
                              hipStream_t stream) {
  (void)in_sizes; (void)n_in; (void)d_ws; (void)ws_size; (void)out_size;
  const float* x = (const float*)d_in[0];
  const float* w_ih0 = (const float*)d_in[1];
  const float* w_hh0 = (const float*)d_in[2];
  const float* b_ih0 = (const float*)d_in[3];
  const float* b_hh0 = (const float*)d_in[4];
  const float* w_ih1 = (const float*)d_in[5];
  const float* w_hh1 = (const float*)d_in[6];
  const float* b_ih1 = (const float*)d_in[7];
  const float* b_hh1 = (const float*)d_in[8];
  const float* w_fc1 = (const float*)d_in[9];
  const float* b_fc1 = (const float*)d_in[10];
  const float* w_fc2 = (const float*)d_in[11];
  const float* b_fc2 = (const float*)d_in[12];

  fused_lstm<<<dim3(8192 / BB), dim3(NTHREADS), 0, stream>>>(
      x, w_ih0, w_hh0, b_ih0, b_hh0, w_ih1, w_hh1, b_ih1, b_hh1,
      w_fc1, b_fc1, w_fc2, b_fc2, (float*)d_out);
}

// Round 10
// 317.793 us; speedup vs baseline: 16.5881x; 1.0621x over previous
//
#include <hip/hip_runtime.h>

// R10 = R9 with cvt_pkrtz return-type fixed via bit_cast.
//  - packed-f32 (float2) activation arithmetic -> v_pk_{add,mul,fma}_f32
//  - v_cvt_pkrtz_f16_f32 for h packing
//  - branchless clamped x-prefetch (no t+1<TT exec-mask churn)
//  - s_setprio(1) around MFMA chains (wave role-split grp0/grp1)
// Structure unchanged: 8-wave layer-split block, BB=16, skewed layers,
// 1 barrier/step, weights in regs, rational 7-trans activations.

#define TT 256
#define II 14
#define BB 16
#define NTHREADS 512
#define XP 40  // xs row pitch (halfs)
#define HP 72  // hbuf row pitch (halfs)
#define LOG2E 1.44269504088896340736f

typedef _Float16 f16x8 __attribute__((ext_vector_type(8)));
typedef _Float16 f16x4 __attribute__((ext_vector_type(4)));
typedef _Float16 f16x2 __attribute__((ext_vector_type(2)));
typedef float f32x4 __attribute__((ext_vector_type(4)));
typedef float f32x2 __attribute__((ext_vector_type(2)));

__device__ __forceinline__ f32x4 MFMA16(f16x8 a, f16x8 b, f32x4 c) {
  return __builtin_amdgcn_mfma_f32_16x16x32_f16(a, b, c, 0, 0, 0);
}

__device__ __forceinline__ float ex2(float x) {
#if __has_builtin(__builtin_amdgcn_exp2f)
  return __builtin_amdgcn_exp2f(x);
#else
  float r; asm("v_exp_f32 %0, %1" : "=v"(r) : "v"(x)); return r;
#endif
}
__device__ __forceinline__ float rcp_(float x) {
#if __has_builtin(__builtin_amdgcn_rcpf)
  return __builtin_amdgcn_rcpf(x);
#else
  float r; asm("v_rcp_f32 %0, %1" : "=v"(r) : "v"(x)); return r;
#endif
}
__device__ __forceinline__ f16x2 cvt_pk(float a, float b) {
#if __has_builtin(__builtin_amdgcn_cvt_pkrtz)
  return __builtin_bit_cast(f16x2, __builtin_amdgcn_cvt_pkrtz(a, b));
#else
  f16x2 r; r[0] = (_Float16)a; r[1] = (_Float16)b; return r;
#endif
}

// Pre-scaled gates (i,f,o: *-log2e ; g: *2log2e), u = 2^s:
//   c' = [c*(1+u_i)(1+u_g) + (u_g-1)(1+u_f)] / [(1+u_f)(1+u_i)(1+u_g)]
//   h  = (u_t-1)/[(1+u_o)(1+u_t)], u_t = 2^(2log2e*c')
// Regular arithmetic on float2 lanes (packed f32 VALU ops).
__device__ __forceinline__ f16x4 lstm_act(f32x4 si, f32x4 sf, f32x4 sg, f32x4 so,
                                          f32x4& cs) {
  f16x4 hp;
#pragma unroll
  for (int p = 0; p < 2; ++p) {
    f32x2 ui, uf, ug, uo;
    ui.x = ex2(si[2 * p]); ui.y = ex2(si[2 * p + 1]);
    uf.x = ex2(sf[2 * p]); uf.y = ex2(sf[2 * p + 1]);
    ug.x = ex2(sg[2 * p]); ug.y = ex2(sg[2 * p + 1]);
    uo.x = ex2(so[2 * p]); uo.y = ex2(so[2 * p + 1]);
    const f32x2 one = {1.0f, 1.0f};
    const f32x2 fi = ui + one;
    const f32x2 ff = uf + one;
    const f32x2 fg = ug + one;
    const f32x2 pig = fi * fg;
    f32x2 cv; cv.x = cs[2 * p]; cv.y = cs[2 * p + 1];
    const f32x2 num = cv * pig + (ug - one) * ff;
    const f32x2 den = pig * ff;
    f32x2 rd; rd.x = rcp_(den.x); rd.y = rcp_(den.y);
    const f32x2 c = num * rd;
    cs[2 * p] = c.x; cs[2 * p + 1] = c.y;
    const f32x2 ctl = c * (f32x2){2.0f * LOG2E, 2.0f * LOG2E};
    f32x2 ut; ut.x = ex2(ctl.x); ut.y = ex2(ctl.y);
    const f32x2 dh = (uo + one) * (ut + one);
    f32x2 rh; rh.x = rcp_(dh.x); rh.y = rcp_(dh.y);
    const f32x2 h = (ut - one) * rh;
    const f16x2 h2 = cvt_pk(h.x, h.y);
    hp[2 * p] = h2[0];
    hp[2 * p + 1] = h2[1];
  }
  return hp;
}

__global__ void __launch_bounds__(NTHREADS, 4) fused_lstm(
    const float* __restrict__ x,
    const float* __restrict__ w_ih0, const float* __restrict__ w_hh0,
    const float* __restrict__ b_ih0, const float* __restrict__ b_hh0,
    const float* __restrict__ w_ih1, const float* __restrict__ w_hh1,
    const float* __restrict__ b_ih1, const float* __restrict__ b_hh1,
    const float* __restrict__ w_fc1, const float* __restrict__ b_fc1,
    const float* __restrict__ w_fc2, const float* __restrict__ b_fc2,
    float* __restrict__ out) {
  // LDS bytes: H1[2] @0 (2x2304) ; H0[2] @4608 (2x2304) ; XS[2] @9216 (2x1280)
  __shared__ char smem[11776];

  const int tid = threadIdx.x;
  const int wv = tid >> 6;
  const int grp = wv >> 2;   // 0: layer-0 waves, 1: layer-1 waves
  const int wl = wv & 3;     // hidden-tile index (16 units)
  const int l = tid & 63;
  const int row16 = l & 15;  // A: M row / B,C,D: N col (batch)
  const int kblk = l >> 4;   // A,B: k-block of 8 / C,D: row-block of 4

  const int b0 = blockIdx.x * BB;

  // ---- per-group weight A-fragments (one layer only), pre-scaled ----
  f16x8 wIn[4][2], wRec[4][2];
  f32x4 bias[4];
#pragma unroll
  for (int gt = 0; gt < 4; ++gt) {
    const float sc = (gt == 2) ? (2.0f * LOG2E) : (-LOG2E);
    const int g = gt * 64 + wl * 16 + row16;
    if (grp == 0) {
      f16x8 v;
#pragma unroll
      for (int j = 0; j < 8; ++j) {
        const int k = kblk * 8 + j;
        v[j] = (k < II) ? (_Float16)(w_ih0[g * II + k] * sc) : (_Float16)0.0f;
      }
      wIn[gt][0] = v;
#pragma unroll
      for (int ks = 0; ks < 2; ++ks) {
        const int ko = ks * 32 + kblk * 8;
        f16x8 vr;
#pragma unroll
        for (int j = 0; j < 8; ++j) vr[j] = (_Float16)(w_hh0[g * 64 + ko + j] * sc);
        wRec[gt][ks] = vr;
      }
    } else {
#pragma unroll
      for (int ks = 0; ks < 2; ++ks) {
        const int ko = ks * 32 + kblk * 8;
        f16x8 vi, vr;
#pragma unroll
        for (int j = 0; j < 8; ++j) vi[j] = (_Float16)(w_ih1[g * 64 + ko + j] * sc);
#pragma unroll
        for (int j = 0; j < 8; ++j) vr[j] = (_Float16)(w_hh1[g * 64 + ko + j] * sc);
        wIn[gt][ks] = vi;
        wRec[gt][ks] = vr;
      }
    }
    const int gb = gt * 64 + wl * 16 + kblk * 4;  // C/D row base
#pragma unroll
    for (int r = 0; r < 4; ++r) {
      bias[gt][r] = (grp == 0) ? (b_ih0[gb + r] + b_hh0[gb + r]) * sc
                               : (b_ih1[gb + r] + b_hh1[gb + r]) * sc;
    }
  }

  for (int i = tid; i < 11776 / 4; i += NTHREADS) ((int*)smem)[i] = 0;

  // x staging: BB*II = 224 slots (grp0 waves)
  const int n0 = tid / II, k0 = tid - n0 * II;
  const bool hasx = tid < BB * II;
  const float* xp0 = x + (size_t)(b0 + (hasx ? n0 : 0)) * (TT * II) + k0;

  _Float16* H1 = (_Float16*)smem;            // [2][1152]
  _Float16* H0 = (_Float16*)(smem + 4608);   // [2][1152]
  _Float16* XS = (_Float16*)(smem + 9216);   // [2][640]

  __syncthreads();  // zeros done
  if (hasx) XS[n0 * XP + k0] = (_Float16)xp0[0];
  __syncthreads();  // x(0) staged

  f32x4 cs = {0.f, 0.f, 0.f, 0.f};

  const int boff = row16 * HP + kblk * 8;           // B-frag offset (halfs)
  const int woff = row16 * HP + wl * 16 + kblk * 4; // C/D publish offset

  // ============ prologue t=0: grp0 computes h0(0) ============
  if (grp == 0) {
    f32x4 acc[4];
#pragma unroll
    for (int gt = 0; gt < 4; ++gt) acc[gt] = bias[gt];
    const f16x8 bx = *(const f16x8*)(XS + row16 * XP + kblk * 8);
    const f16x8 bhA = *(const f16x8*)(H0 + 1152 + boff);  // zeros
    const f16x8 bhB = *(const f16x8*)(H0 + 1152 + 32 + boff);
    __builtin_amdgcn_s_setprio(1);
#pragma unroll
    for (int gt = 0; gt < 4; ++gt) {
      acc[gt] = MFMA16(wIn[gt][0], bx, acc[gt]);
      acc[gt] = MFMA16(wRec[gt][0], bhA, acc[gt]);
      acc[gt] = MFMA16(wRec[gt][1], bhB, acc[gt]);
    }
    __builtin_amdgcn_s_setprio(0);
    const float xn = hasx ? (float)xp0[II] : 0.0f;  // x(1)
    const f16x4 hp = lstm_act(acc[0], acc[1], acc[2], acc[3], cs);
    *(f16x4*)(H0 + woff) = hp;  // H0[0]
    if (hasx) XS[640 + n0 * XP + k0] = (_Float16)xn;
  }
  __syncthreads();

  // ============ main loop t=1..TT-1: grp0 L0(t), grp1 L1(t-1) ============
#pragma unroll 2
  for (int t = 1; t < TT; ++t) {
    const int pc = t & 1, pp = pc ^ 1;
    if (grp == 0) {
      f32x4 acc[4];
#pragma unroll
      for (int gt = 0; gt < 4; ++gt) acc[gt] = bias[gt];
      const f16x8 bx = *(const f16x8*)(XS + pc * 640 + row16 * XP + kblk * 8);
      const f16x8 bhA = *(const f16x8*)(H0 + pp * 1152 + boff);
      const f16x8 bhB = *(const f16x8*)(H0 + pp * 1152 + 32 + boff);
      __builtin_amdgcn_s_setprio(1);
#pragma unroll
      for (int gt = 0; gt < 4; ++gt) {
        acc[gt] = MFMA16(wIn[gt][0], bx, acc[gt]);
        acc[gt] = MFMA16(wRec[gt][0], bhA, acc[gt]);
        acc[gt] = MFMA16(wRec[gt][1], bhB, acc[gt]);
      }
      __builtin_amdgcn_s_setprio(0);
      // branchless clamped prefetch of x(t+1)
      const int tn = (t + 1 < TT) ? (t + 1) : (TT - 1);
      const float xn = hasx ? xp0[(size_t)tn * II] : 0.0f;
      const f16x4 hp = lstm_act(acc[0], acc[1], acc[2], acc[3], cs);
      *(f16x4*)(H0 + pc * 1152 + woff) = hp;  // h0(t)
      if (hasx) XS[pp * 640 + n0 * XP + k0] = (_Float16)xn;
    } else {
      f32x4 acc[4];
#pragma unroll
      for (int gt = 0; gt < 4; ++gt) acc[gt] = bias[gt];
      const f16x8 bgA = *(const f16x8*)(H0 + pp * 1152 + boff);  // h0(t-1)
      const f16x8 bgB = *(const f16x8*)(H0 + pp * 1152 + 32 + boff);
      const f16x8 bhA = *(const f16x8*)(H1 + pc * 1152 + boff);  // h1(t-2)
      const f16x8 bhB = *(const f16x8*)(H1 + pc * 1152 + 32 + boff);
      __builtin_amdgcn_s_setprio(1);
#pragma unroll
      for (int gt = 0; gt < 4; ++gt) {
        acc[gt] = MFMA16(wIn[gt][0], bgA, acc[gt]);
        acc[gt] = MFMA16(wIn[gt][1], bgB, acc[gt]);
        acc[gt] = MFMA16(wRec[gt][0], bhA, acc[gt]);
        acc[gt] = MFMA16(wRec[gt][1], bhB, acc[gt]);
      }
      __builtin_amdgcn_s_setprio(0);
      const f16x4 hp = lstm_act(acc[0], acc[1], acc[2], acc[3], cs);
      *(f16x4*)(H1 + pp * 1152 + woff) = hp;  // h1(t-1)
    }
    __syncthreads();
  }

  // ============ epilogue: grp1 computes h1(TT-1) ============
  if (grp == 1) {  // pc=0, pp=1
    f32x4 acc[4];
#pragma unroll
    for (int gt = 0; gt < 4; ++gt) acc[gt] = bias[gt];
    const f16x8 bgA = *(const f16x8*)(H0 + 1152 + boff);  // h0(TT-1)
    const f16x8 bgB = *(const f16x8*)(H0 + 1152 + 32 + boff);
    const f16x8 bhA = *(const f16x8*)(H1 + boff);          // h1(TT-2)
    const f16x8 bhB = *(const f16x8*)(H1 + 32 + boff);
    __builtin_amdgcn_s_setprio(1);
#pragma unroll
    for (int gt = 0; gt < 4; ++gt) {
      acc[gt] = MFMA16(wIn[gt][0], bgA, acc[gt]);
      acc[gt] = MFMA16(wIn[gt][1], bgB, acc[gt]);
      acc[gt] = MFMA16(wRec[gt][0], bhA, acc[gt]);
      acc[gt] = MFMA16(wRec[gt][1], bhB, acc[gt]);
    }
    __builtin_amdgcn_s_setprio(0);
    const f16x4 hp = lstm_act(acc[0], acc[1], acc[2], acc[3], cs);
    *(f16x4*)(H1 + 1152 + woff) = hp;  // h1(TT-1)
  }
  __syncthreads();

  // ============ FC head (512 threads) ============
  const _Float16* h1f = (const _Float16*)(smem + 2304);  // H1[1]
  float* zbuf = (float*)(smem + 4608);                   // overlays H0 (dead)
  {
    float4 w1r[16];
#pragma unroll
    for (int k4 = 0; k4 < 16; ++k4)
      w1r[k4] = *(const float4*)(w_fc1 + l * 64 + k4 * 4);
    const float b1l = b_fc1[l];
#pragma unroll
    for (int bi = 0; bi < 2; ++bi) {
      const int n = wv * 2 + bi;
      float s = b1l;
#pragma unroll
      for (int k4 = 0; k4 < 16; ++k4) {
        const float4 wq = w1r[k4];
        s = fmaf((float)h1f[n * HP + k4 * 4 + 0], wq.x, s);
        s = fmaf((float)h1f[n * HP + k4 * 4 + 1], wq.y, s);
        s = fmaf((float)h1f[n * HP + k4 * 4 + 2], wq.z, s);
        s = fmaf((float)h1f[n * HP + k4 * 4 + 3], wq.w, s);
      }
      zbuf[n * 64 + l] = fmaxf(s, 0.0f);
    }
  }
  __syncthreads();
  if (tid < 2 * BB) {
    const int n = tid >> 1, cc = tid & 1;
    float s = b_fc2[cc];
    for (int j = 0; j < 64; ++j) s = fmaf(w_fc2[cc * 64 + j], zbuf[n * 64 + j], s);
    out[(size_t)(b0 + n) * 2 + cc] = s;
  }
}

extern "C" void kernel_launch(void* const* d_in, const int* in_sizes, int n_in,
                              void* d_out, int out_size, void* d_ws, size_t ws_size,
                              hipStream_t stream) {
  (void)in_sizes; (void)n_in; (void)d_ws; (void)ws_size; (void)out_size;
  const float* x = (const float*)d_in[0];
  const float* w_ih0 = (const float*)d_in[1];
  const float* w_hh0 = (const float*)d_in[2];
  const float* b_ih0 = (const float*)d_in[3];
  const float* b_hh0 = (const float*)d_in[4];
  const float* w_ih1 = (const float*)d_in[5];
  const float* w_hh1 = (const float*)d_in[6];
  const float* b_ih1 = (const float*)d_in[7];
  const float* b_hh1 = (const float*)d_in[8];
  const float* w_fc1 = (const float*)d_in[9];
  const float* b_fc1 = (const float*)d_in[10];
  const float* w_fc2 = (const float*)d_in[11];
  const float* b_fc2 = (const float*)d_in[12];

  fused_lstm<<<dim3(8192 / BB), dim3(NTHREADS), 0, stream>>>(
      x, w_ih0, w_hh0, b_ih0, b_hh0, w_ih1, w_hh1, b_ih1, b_hh1,
      w_fc1, b_fc1, w_fc2, b_fc2, (float*)d_out);
}